// Round 6
// baseline (189.956 us; speedup 1.0000x reference)
//
#include <hip/hip_runtime.h>
#include <cstddef>
#include <cstdint>

// B=256, N=32, F=40, H=M=100, EF=4, OUT=128, 3 passes.
#define B_   256
#define N_   32
#define F_   40
#define H_   100
#define OUT_ 128
#define CAP_ 8
#define TB   1024         // 16 waves/block -> 4 waves/SIMD
#define XCS  168          // Xcat row stride (shorts): k 0..159 (+8 pad), 16B-mult
#define XMS  136          // Xm / Xy row stride (shorts): k 0..127 (+8 pad)
#define NBLK 343          // A-fragment blocks in workspace

using bf16x8 = __attribute__((ext_vector_type(8))) short;   // 8 bf16 (4 VGPRs)
using f32x4  = __attribute__((ext_vector_type(4))) float;   // MFMA C/D

__device__ __forceinline__ float sigmoidf_(float x){ return 1.0f/(1.0f+__expf(-x)); }
__device__ __forceinline__ float bf2f(short s){ return __uint_as_float(((uint32_t)(uint16_t)s)<<16); }
__device__ __forceinline__ short f2bf(float x){            // round-to-nearest-even
  uint32_t u = __float_as_uint(x);
  return (short)((u + 0x7FFFu + ((u>>16)&1u))>>16);
}
__device__ __forceinline__ void bsplit(float x, short& hi, short& lo){
  hi = f2bf(x);
  lo = f2bf(x - bf2f(hi));
}

// ---------------------------------------------------------------------------
// Pre-pack every weight matrix into MFMA A-operand fragments, hi/lo bf16.
// Block table (each block = one (tile,kstep): 64 lanes x {8 hi, 8 lo} shorts):
//   [0,112)   W_msg  : t<4, jmt<7, ks<4     A[m][k]=W_msg[m, k, t]
//   [112,280) GRU    : mat<6 (ihr,ihz,ihn,hhr,hhz,hhn), jmt<7, ks<4
//   [280,315) Wg^T   : jmt<7, ks<5 (K=140)  A[j][k]=Wg[k, j]
//   [315,343) We^T   : jmt<7, ks<4          A[j][k]=We[k, j]
// Lane layout: A[m=lane&15][k=(lane>>4)*8+j]. OOR rows/cols stored as 0.
// ---------------------------------------------------------------------------
__global__ void prep_frags(const float* __restrict__ Wmsg,
                           const float* __restrict__ Wih,
                           const float* __restrict__ Whh,
                           const float* __restrict__ Wg,
                           const float* __restrict__ We,
                           short* __restrict__ AF){
  int t0 = blockIdx.x*blockDim.x + threadIdx.x;
  if (t0 >= NBLK*64) return;
  int blk = t0>>6, lane = t0&63;
  int m = lane&15, q = lane>>4;
  short* dst = AF + (size_t)blk*1024 + lane*16;
  for (int j=0;j<8;++j){
    int kl = q*8 + j;
    float v = 0.0f;
    if (blk < 112){
      int t = blk/28, rem = blk%28, jmt = rem>>2, ks = rem&3;
      int mg = jmt*16+m, k = ks*32+kl;
      if (mg<100 && k<100) v = Wmsg[(mg*100+k)*4 + t];
    } else if (blk < 280){
      int bb = blk-112, mat = bb/28, rem = bb%28, jmt = rem>>2, ks = rem&3;
      int mg = jmt*16+m, k = ks*32+kl;
      if (mg<100 && k<100)
        v = (mat<3) ? Wih[(mat*100+mg)*100+k] : Whh[((mat-3)*100+mg)*100+k];
    } else if (blk < 315){
      int bb = blk-280, jmt = bb/5, ks = bb%5;
      int mg = jmt*16+m, k = ks*32+kl;
      if (mg<100 && k<140) v = Wg[k*100+mg];
    } else {
      int bb = blk-315, jmt = bb>>2, ks = bb&3;
      int mg = jmt*16+m, k = ks*32+kl;
      if (mg<100 && k<100) v = We[k*100+mg];
    }
    short hi,lo; bsplit(v,hi,lo);
    dst[j] = hi; dst[8+j] = lo;
  }
}

// B-operand fragment from LDS [n][k] bf16: lane holds B[k=(lane>>4)*8+j][n=lane&15]
__device__ __forceinline__ bf16x8 ldB(const short* X, int stride, int nt, int ks, int lane){
  int n = nt*16 + (lane&15);
  return *(const bf16x8*)&X[n*stride + ks*32 + (lane>>4)*8];
}
// C += Ahi*Bhi + Ahi*Blo + Alo*Bhi  (split-bf16 triple product)
__device__ __forceinline__ f32x4 mm3(const short* __restrict__ AF, int blk, int lane,
                                     bf16x8 bh, bf16x8 bl, f32x4 c){
  const short* pa = AF + (size_t)blk*1024 + lane*16;
  bf16x8 ah = *(const bf16x8*)pa;
  bf16x8 al = *(const bf16x8*)(pa+8);
  c = __builtin_amdgcn_mfma_f32_16x16x32_bf16(ah, bh, c, 0,0,0);
  c = __builtin_amdgcn_mfma_f32_16x16x32_bf16(ah, bl, c, 0,0,0);
  c = __builtin_amdgcn_mfma_f32_16x16x32_bf16(al, bh, c, 0,0,0);
  return c;
}

// ---------------------------------------------------------------------------
// Fused MPNN, one block per batch, 1024 threads (16 waves).
// 14 MFMA tile-tasks (7 jm-tiles x 2 n-tiles); wave w owns task w (w<14).
// Y-gather is wave-uniform-n / lane-contiguous-k (conflict-free int reads).
// ---------------------------------------------------------------------------
__global__ __launch_bounds__(TB) void mpnn_mfma(
    const float* __restrict__ nodes, const float* __restrict__ edges,
    const short* __restrict__ AF,
    const float* __restrict__ b_ih, const float* __restrict__ b_hh,
    const float* __restrict__ bg, const float* __restrict__ be,
    const float* __restrict__ Wo, const float* __restrict__ bo,
    float* __restrict__ out){
  const int b = blockIdx.x;
  const int tid = threadIdx.x;
  const int lane = tid & 63;
  const int w = tid >> 6;

  __shared__ short XcH[32*XCS], XcL[32*XCS];   // cat: h(0..99) | nodes(100..139) | 0
  __shared__ short XmH[32*XMS], XmL[32*XMS];   // messages
  __shared__ short XyH[32*XMS], XyL[32*XMS];   // per-type aggregated Y_t
  __shared__ float sh_ge[H_];
  __shared__ float sh_rowsum[N_];
  __shared__ int   sh_cnt[N_];
  __shared__ int   sh_gt[N_][CAP_];            // packed (g<<2)|t
  __shared__ float sh_w[N_][CAP_];

  // ---- zero LDS ------------------------------------------------------------
  for (int i=tid;i<(32*XCS)/2;i+=TB){ ((int*)XcH)[i]=0; ((int*)XcL)[i]=0; }
  for (int i=tid;i<(32*XMS)/2;i+=TB){ ((int*)XmH)[i]=0; ((int*)XmL)[i]=0;
                                      ((int*)XyH)[i]=0; ((int*)XyL)[i]=0; }
  if (tid < H_) sh_ge[tid]=0.0f;
  if (tid < N_){ sh_cnt[tid]=0; sh_rowsum[tid]=0.0f; }
  __syncthreads();

  // ---- per-node neighbor lists + node staging ------------------------------
  for (int p=tid; p<N_*N_; p+=TB){
    int n = p>>5, g = p&31;
    const float4 ev = *(const float4*)(edges + (((size_t)b*N_+n)*N_+g)*4);
    float adj = ev.x+ev.y+ev.z+ev.w;
    if (adj != 0.0f){
      atomicAdd(&sh_rowsum[n], adj);
      float ef[4] = {ev.x,ev.y,ev.z,ev.w};
      for (int f=0; f<4; ++f)
        if (ef[f] != 0.0f){
          int s = atomicAdd(&sh_cnt[n],1);
          if (s<CAP_){ sh_gt[n][s]=(g<<2)|f; sh_w[n][s]=ef[f]; }
        }
    }
  }
  for (int p=tid; p<N_*F_; p+=TB){
    int n = p/F_, f = p%F_;
    float x = nodes[((size_t)b*N_+n)*F_ + f];
    short hi,lo; bsplit(x,hi,lo);
    XcH[n*XCS+f]=hi;      XcL[n*XCS+f]=lo;        // h init rows 0..39
    XcH[n*XCS+100+f]=hi;  XcL[n*XCS+100+f]=lo;    // cat-tail rows 100..139
  }
  __syncthreads();

  const int jmt = w>>1, nt = w&1;                 // task (w<14)
  const bool task = (w < 14);

  for (int pass=0; pass<3; ++pass){
    // ---- messages: C_msg += sum_t W_t * Y_t --------------------------------
    f32x4 Cm = (f32x4)0.0f;
    for (int t=0;t<4;++t){
      // build Y_t: wave-uniform n, lanes along k (packed int = 2 bf16)
      for (int it=0; it<2; ++it){
        int idx = tid + it*TB;                 // 0..2047
        int n = idx >> 6;                      // wave-uniform
        int kp = idx & 63;                     // int index: k = 2kp, 2kp+1
        int cnt = sh_cnt[n] < CAP_ ? sh_cnt[n] : CAP_;
        float s0=0.0f, s1=0.0f;
        for (int e=0;e<cnt;++e){
          int gt = sh_gt[n][e];                // wave-uniform -> scalar branch
          if ((gt&3)==t){
            int g = gt>>2; float wv = sh_w[n][e];
            int hh = ((const int*)(XcH + g*XCS))[kp];
            int ll = ((const int*)(XcL + g*XCS))[kp];
            float h0 = bf2f((short)(hh&0xffff)) + bf2f((short)(ll&0xffff));
            float h1 = bf2f((short)(hh>>16))    + bf2f((short)(ll>>16));
            s0 += wv*h0; s1 += wv*h1;
          }
        }
        short a,bs,c,d; bsplit(s0,a,bs); bsplit(s1,c,d);
        ((int*)(XyH + n*XMS))[kp] = (int)((uint16_t)a | ((uint32_t)(uint16_t)c<<16));
        ((int*)(XyL + n*XMS))[kp] = (int)((uint16_t)bs | ((uint32_t)(uint16_t)d<<16));
      }
      __syncthreads();
      if (task){
        for (int ks=0;ks<4;++ks){
          bf16x8 bh = ldB(XyH,XMS,nt,ks,lane), bl = ldB(XyL,XMS,nt,ks,lane);
          Cm = mm3(AF, (t*7+jmt)*4+ks, lane, bh, bl, Cm);
        }
      }
      __syncthreads();                         // Y_t consumed; safe to rebuild
    }
    // write messages -> Xm (rows<100)
    if (task){
      int n = nt*16+(lane&15);
      for (int r=0;r<4;++r){
        int row = jmt*16 + (lane>>4)*4 + r;
        if (row<100){
          short hi,lo; bsplit(Cm[r],hi,lo);
          XmH[n*XMS+row]=hi; XmL[n*XMS+row]=lo;
        }
      }
    }
    __syncthreads();
    // ---- GRU gate GEMMs: Cr=ir+hr, Cz=iz+hz, Ci=in, Ch=hn ------------------
    f32x4 Cr=(f32x4)0.0f, Cz=(f32x4)0.0f, Ci=(f32x4)0.0f, Ch=(f32x4)0.0f;
    if (task){
      for (int ks=0;ks<4;++ks){
        bf16x8 bmh = ldB(XmH,XMS,nt,ks,lane), bml = ldB(XmL,XMS,nt,ks,lane);
        bf16x8 bhh = ldB(XcH,XCS,nt,ks,lane), bhl = ldB(XcL,XCS,nt,ks,lane);
        int base = 112 + jmt*4 + ks;
        Cr = mm3(AF, base + 0*28, lane, bmh, bml, Cr);  // ih_r
        Cr = mm3(AF, base + 3*28, lane, bhh, bhl, Cr);  // hh_r
        Cz = mm3(AF, base + 1*28, lane, bmh, bml, Cz);  // ih_z
        Cz = mm3(AF, base + 4*28, lane, bhh, bhl, Cz);  // hh_z
        Ci = mm3(AF, base + 2*28, lane, bmh, bml, Ci);  // ih_n
        Ch = mm3(AF, base + 5*28, lane, bhh, bhl, Ch);  // hh_n
      }
    }
    __syncthreads();                           // all Xc/Xm reads done
    // ---- GRU elementwise: update h rows of Xcat in place -------------------
    if (task){
      int n = nt*16+(lane&15);
      bool msk = (sh_rowsum[n] != 0.0f);
      for (int r=0;r<4;++r){
        int row = jmt*16 + (lane>>4)*4 + r;
        if (row<100){
          float ho = bf2f(XcH[n*XCS+row]) + bf2f(XcL[n*XCS+row]);
          float rr = sigmoidf_(Cr[r] + b_ih[row]     + b_hh[row]);
          float zz = sigmoidf_(Cz[r] + b_ih[100+row] + b_hh[100+row]);
          float nn = tanhf(Ci[r] + b_ih[200+row] + rr*(Ch[r] + b_hh[200+row]));
          float hnew = (1.0f-zz)*nn + zz*ho;
          if (!msk) hnew = ho;
          short hi,lo; bsplit(hnew,hi,lo);
          XcH[n*XCS+row]=hi; XcL[n*XCS+row]=lo;
        }
      }
    }
    __syncthreads();
  }

  // ---- readout: gate = sig(cat@Wg+bg), emb = gate*(h@We+be), masked sum ----
  f32x4 Cg=(f32x4)0.0f, Ce=(f32x4)0.0f;
  if (task){
    for (int ks=0;ks<5;++ks){                  // K=140: Xcat carries cat rows
      bf16x8 bh = ldB(XcH,XCS,nt,ks,lane), bl = ldB(XcL,XCS,nt,ks,lane);
      Cg = mm3(AF, 280 + jmt*5 + ks, lane, bh, bl, Cg);
    }
    for (int ks=0;ks<4;++ks){                  // K=100: We zero-pad kills rows>=100
      bf16x8 bh = ldB(XcH,XCS,nt,ks,lane), bl = ldB(XcL,XCS,nt,ks,lane);
      Ce = mm3(AF, 315 + jmt*4 + ks, lane, bh, bl, Ce);
    }
    int n = nt*16+(lane&15);
    bool msk = (sh_rowsum[n] != 0.0f);
    for (int r=0;r<4;++r){
      int row = jmt*16 + (lane>>4)*4 + r;
      float v = 0.0f;
      if (row<100){
        float gate = sigmoidf_(Cg[r] + bg[row]);
        float emb  = gate*(Ce[r] + be[row]);
        v = msk ? emb : 0.0f;
      }
      v += __shfl_xor(v, 1);                   // reduce across 16 cols
      v += __shfl_xor(v, 2);
      v += __shfl_xor(v, 4);
      v += __shfl_xor(v, 8);
      if (row<100 && (lane&15)==0) atomicAdd(&sh_ge[row], v);
    }
  }
  __syncthreads();
  // ---- out = graph_emb @ Wo + bo -------------------------------------------
  if (tid < OUT_){
    float s = bo[tid];
#pragma unroll 4
    for (int k=0;k<H_;++k) s += sh_ge[k]*Wo[k*OUT_+tid];
    out[(size_t)b*OUT_ + tid] = s;
  }
}

extern "C" void kernel_launch(void* const* d_in, const int* in_sizes, int n_in,
                              void* d_out, int out_size, void* d_ws, size_t ws_size,
                              hipStream_t stream){
  const float* nodes = (const float*)d_in[0];
  const float* edges = (const float*)d_in[1];
  const float* W_msg = (const float*)d_in[2];
  const float* W_ih  = (const float*)d_in[3];
  const float* W_hh  = (const float*)d_in[4];
  const float* b_ih  = (const float*)d_in[5];
  const float* b_hh  = (const float*)d_in[6];
  const float* Wg    = (const float*)d_in[7];
  const float* bg    = (const float*)d_in[8];
  const float* We    = (const float*)d_in[9];
  const float* be    = (const float*)d_in[10];
  const float* Wo    = (const float*)d_in[11];
  const float* bo    = (const float*)d_in[12];

  short* AF = (short*)d_ws;                 // 343*1024 shorts = 686 KB

  prep_frags<<<(NBLK*64 + 255)/256, 256, 0, stream>>>(W_msg, W_ih, W_hh, Wg, We, AF);
  mpnn_mfma<<<B_, TB, 0, stream>>>(nodes, edges, AF, b_ih, b_hh, bg, be, Wo, bo,
                                   (float*)d_out);
}

// Round 7
// 188.268 us; speedup vs baseline: 1.0090x; 1.0090x over previous
//
#include <hip/hip_runtime.h>
#include <cstddef>
#include <cstdint>

// B=256, N=32, F=40, H=M=100, EF=4, OUT=128, 3 passes.
#define B_   256
#define N_   32
#define F_   40
#define H_   100
#define OUT_ 128
#define CAP_ 8
#define TB   1024         // 16 waves/block -> 4 waves/SIMD, 1 block/CU
#define XCS  168          // Xcat row stride (shorts): k 0..159 (+8 pad), 16B-mult
#define XMS  136          // Xm / Xy row stride (shorts): k 0..127 (+8 pad)
#define NBLK 343          // A-fragment blocks in workspace

using bf16x8 = __attribute__((ext_vector_type(8))) short;   // 8 bf16 (4 VGPRs)
using f32x4  = __attribute__((ext_vector_type(4))) float;   // MFMA C/D

__device__ __forceinline__ float sigmoidf_(float x){ return 1.0f/(1.0f+__expf(-x)); }
__device__ __forceinline__ float bf2f(short s){ return __uint_as_float(((uint32_t)(uint16_t)s)<<16); }
__device__ __forceinline__ short f2bf(float x){            // round-to-nearest-even
  uint32_t u = __float_as_uint(x);
  return (short)((u + 0x7FFFu + ((u>>16)&1u))>>16);
}
__device__ __forceinline__ void bsplit(float x, short& hi, short& lo){
  hi = f2bf(x);
  lo = f2bf(x - bf2f(hi));
}

// ---------------------------------------------------------------------------
// Pre-pack every weight matrix into MFMA A-operand fragments, hi/lo bf16.
// Block table (each block = one (tile,kstep): 64 lanes x {8 hi, 8 lo} shorts):
//   [0,112)   W_msg  : t<4, jmt<7, ks<4     A[m][k]=W_msg[m, k, t]
//   [112,280) GRU    : mat<6 (ihr,ihz,ihn,hhr,hhz,hhn), jmt<7, ks<4
//   [280,315) Wg^T   : jmt<7, ks<5 (K=140)  A[j][k]=Wg[k, j]
//   [315,343) We^T   : jmt<7, ks<4          A[j][k]=We[k, j]
// Lane layout: A[m=lane&15][k=(lane>>4)*8+j]. OOR rows/cols stored as 0.
// ---------------------------------------------------------------------------
__global__ void prep_frags(const float* __restrict__ Wmsg,
                           const float* __restrict__ Wih,
                           const float* __restrict__ Whh,
                           const float* __restrict__ Wg,
                           const float* __restrict__ We,
                           short* __restrict__ AF){
  int t0 = blockIdx.x*blockDim.x + threadIdx.x;
  if (t0 >= NBLK*64) return;
  int blk = t0>>6, lane = t0&63;
  int m = lane&15, q = lane>>4;
  short* dst = AF + (size_t)blk*1024 + lane*16;
  for (int j=0;j<8;++j){
    int kl = q*8 + j;
    float v = 0.0f;
    if (blk < 112){
      int t = blk/28, rem = blk%28, jmt = rem>>2, ks = rem&3;
      int mg = jmt*16+m, k = ks*32+kl;
      if (mg<100 && k<100) v = Wmsg[(mg*100+k)*4 + t];
    } else if (blk < 280){
      int bb = blk-112, mat = bb/28, rem = bb%28, jmt = rem>>2, ks = rem&3;
      int mg = jmt*16+m, k = ks*32+kl;
      if (mg<100 && k<100)
        v = (mat<3) ? Wih[(mat*100+mg)*100+k] : Whh[((mat-3)*100+mg)*100+k];
    } else if (blk < 315){
      int bb = blk-280, jmt = bb/5, ks = bb%5;
      int mg = jmt*16+m, k = ks*32+kl;
      if (mg<100 && k<140) v = Wg[k*100+mg];
    } else {
      int bb = blk-315, jmt = bb>>2, ks = bb&3;
      int mg = jmt*16+m, k = ks*32+kl;
      if (mg<100 && k<100) v = We[k*100+mg];
    }
    short hi,lo; bsplit(v,hi,lo);
    dst[j] = hi; dst[8+j] = lo;
  }
}

// B-operand fragment from LDS [n][k] bf16: lane holds B[k=(lane>>4)*8+j][n=lane&15]
__device__ __forceinline__ bf16x8 ldB(const short* X, int stride, int nt, int ks, int lane){
  int n = nt*16 + (lane&15);
  return *(const bf16x8*)&X[n*stride + ks*32 + (lane>>4)*8];
}
// C += Ahi*Bhi + Ahi*Blo + Alo*Bhi  (split-bf16 triple product)
__device__ __forceinline__ f32x4 mm3(const short* __restrict__ AF, int blk, int lane,
                                     bf16x8 bh, bf16x8 bl, f32x4 c){
  const short* pa = AF + (size_t)blk*1024 + lane*16;
  bf16x8 ah = *(const bf16x8*)pa;
  bf16x8 al = *(const bf16x8*)(pa+8);
  c = __builtin_amdgcn_mfma_f32_16x16x32_bf16(ah, bh, c, 0,0,0);
  c = __builtin_amdgcn_mfma_f32_16x16x32_bf16(ah, bl, c, 0,0,0);
  c = __builtin_amdgcn_mfma_f32_16x16x32_bf16(al, bh, c, 0,0,0);
  return c;
}

// ---------------------------------------------------------------------------
// Fused MPNN, one block per batch, 1024 threads (16 waves).
// 14 MFMA tile-tasks (7 jm-tiles x 2 n-tiles); wave w owns task w (w<14).
// Y-gather is wave-uniform-n / lane-contiguous-k (conflict-free int reads).
// __launch_bounds__(1024,4): 4 waves/EU == our actual residency (grid=1
// block/CU) -> VGPR cap 128. R6's bare (1024) capped VGPR at 64 and spilled
// the MFMA accumulators (57 MB scratch WRITE_SIZE).
// ---------------------------------------------------------------------------
__global__ __launch_bounds__(TB, 4) void mpnn_mfma(
    const float* __restrict__ nodes, const float* __restrict__ edges,
    const short* __restrict__ AF,
    const float* __restrict__ b_ih, const float* __restrict__ b_hh,
    const float* __restrict__ bg, const float* __restrict__ be,
    const float* __restrict__ Wo, const float* __restrict__ bo,
    float* __restrict__ out){
  const int b = blockIdx.x;
  const int tid = threadIdx.x;
  const int lane = tid & 63;
  const int w = tid >> 6;

  __shared__ short XcH[32*XCS], XcL[32*XCS];   // cat: h(0..99) | nodes(100..139) | 0
  __shared__ short XmH[32*XMS], XmL[32*XMS];   // messages
  __shared__ short XyH[32*XMS], XyL[32*XMS];   // per-type aggregated Y_t
  __shared__ float sh_ge[H_];
  __shared__ float sh_rowsum[N_];
  __shared__ int   sh_cnt[N_];
  __shared__ int   sh_gt[N_][CAP_];            // packed (g<<2)|t
  __shared__ float sh_w[N_][CAP_];

  // ---- zero LDS ------------------------------------------------------------
  for (int i=tid;i<(32*XCS)/2;i+=TB){ ((int*)XcH)[i]=0; ((int*)XcL)[i]=0; }
  for (int i=tid;i<(32*XMS)/2;i+=TB){ ((int*)XmH)[i]=0; ((int*)XmL)[i]=0;
                                      ((int*)XyH)[i]=0; ((int*)XyL)[i]=0; }
  if (tid < H_) sh_ge[tid]=0.0f;
  if (tid < N_){ sh_cnt[tid]=0; sh_rowsum[tid]=0.0f; }
  __syncthreads();

  // ---- per-node neighbor lists + node staging ------------------------------
  for (int p=tid; p<N_*N_; p+=TB){
    int n = p>>5, g = p&31;
    const float4 ev = *(const float4*)(edges + (((size_t)b*N_+n)*N_+g)*4);
    float adj = ev.x+ev.y+ev.z+ev.w;
    if (adj != 0.0f){
      atomicAdd(&sh_rowsum[n], adj);
      float ef[4] = {ev.x,ev.y,ev.z,ev.w};
      for (int f=0; f<4; ++f)
        if (ef[f] != 0.0f){
          int s = atomicAdd(&sh_cnt[n],1);
          if (s<CAP_){ sh_gt[n][s]=(g<<2)|f; sh_w[n][s]=ef[f]; }
        }
    }
  }
  for (int p=tid; p<N_*F_; p+=TB){
    int n = p/F_, f = p%F_;
    float x = nodes[((size_t)b*N_+n)*F_ + f];
    short hi,lo; bsplit(x,hi,lo);
    XcH[n*XCS+f]=hi;      XcL[n*XCS+f]=lo;        // h init rows 0..39
    XcH[n*XCS+100+f]=hi;  XcL[n*XCS+100+f]=lo;    // cat-tail rows 100..139
  }
  __syncthreads();

  const int jmt = w>>1, nt = w&1;                 // task (w<14)
  const bool task = (w < 14);

  for (int pass=0; pass<3; ++pass){
    // ---- messages: C_msg += sum_t W_t * Y_t --------------------------------
    f32x4 Cm = (f32x4)0.0f;
    for (int t=0;t<4;++t){
      // build Y_t: wave-uniform n, lanes along k (packed int = 2 bf16)
      for (int it=0; it<2; ++it){
        int idx = tid + it*TB;                 // 0..2047
        int n = idx >> 6;                      // wave-uniform
        int kp = idx & 63;                     // int index: k = 2kp, 2kp+1
        int cnt = sh_cnt[n] < CAP_ ? sh_cnt[n] : CAP_;
        float s0=0.0f, s1=0.0f;
        for (int e=0;e<cnt;++e){
          int gt = sh_gt[n][e];                // wave-uniform -> scalar branch
          if ((gt&3)==t){
            int g = gt>>2; float wv = sh_w[n][e];
            int hh = ((const int*)(XcH + g*XCS))[kp];
            int ll = ((const int*)(XcL + g*XCS))[kp];
            float h0 = bf2f((short)(hh&0xffff)) + bf2f((short)(ll&0xffff));
            float h1 = bf2f((short)(hh>>16))    + bf2f((short)(ll>>16));
            s0 += wv*h0; s1 += wv*h1;
          }
        }
        short a,bs,c,d; bsplit(s0,a,bs); bsplit(s1,c,d);
        ((int*)(XyH + n*XMS))[kp] = (int)((uint16_t)a | ((uint32_t)(uint16_t)c<<16));
        ((int*)(XyL + n*XMS))[kp] = (int)((uint16_t)bs | ((uint32_t)(uint16_t)d<<16));
      }
      __syncthreads();
      if (task){
        for (int ks=0;ks<4;++ks){
          bf16x8 bh = ldB(XyH,XMS,nt,ks,lane), bl = ldB(XyL,XMS,nt,ks,lane);
          Cm = mm3(AF, (t*7+jmt)*4+ks, lane, bh, bl, Cm);
        }
      }
      __syncthreads();                         // Y_t consumed; safe to rebuild
    }
    // write messages -> Xm (rows<100)
    if (task){
      int n = nt*16+(lane&15);
      for (int r=0;r<4;++r){
        int row = jmt*16 + (lane>>4)*4 + r;
        if (row<100){
          short hi,lo; bsplit(Cm[r],hi,lo);
          XmH[n*XMS+row]=hi; XmL[n*XMS+row]=lo;
        }
      }
    }
    __syncthreads();
    // ---- GRU gate GEMMs: Cr=ir+hr, Cz=iz+hz, Ci=in, Ch=hn ------------------
    f32x4 Cr=(f32x4)0.0f, Cz=(f32x4)0.0f, Ci=(f32x4)0.0f, Ch=(f32x4)0.0f;
    if (task){
      for (int ks=0;ks<4;++ks){
        bf16x8 bmh = ldB(XmH,XMS,nt,ks,lane), bml = ldB(XmL,XMS,nt,ks,lane);
        bf16x8 bhh = ldB(XcH,XCS,nt,ks,lane), bhl = ldB(XcL,XCS,nt,ks,lane);
        int base = 112 + jmt*4 + ks;
        Cr = mm3(AF, base + 0*28, lane, bmh, bml, Cr);  // ih_r
        Cr = mm3(AF, base + 3*28, lane, bhh, bhl, Cr);  // hh_r
        Cz = mm3(AF, base + 1*28, lane, bmh, bml, Cz);  // ih_z
        Cz = mm3(AF, base + 4*28, lane, bhh, bhl, Cz);  // hh_z
        Ci = mm3(AF, base + 2*28, lane, bmh, bml, Ci);  // ih_n
        Ch = mm3(AF, base + 5*28, lane, bhh, bhl, Ch);  // hh_n
      }
    }
    __syncthreads();                           // all Xc/Xm reads done
    // ---- GRU elementwise: update h rows of Xcat in place -------------------
    if (task){
      int n = nt*16+(lane&15);
      bool msk = (sh_rowsum[n] != 0.0f);
      for (int r=0;r<4;++r){
        int row = jmt*16 + (lane>>4)*4 + r;
        if (row<100){
          float ho = bf2f(XcH[n*XCS+row]) + bf2f(XcL[n*XCS+row]);
          float rr = sigmoidf_(Cr[r] + b_ih[row]     + b_hh[row]);
          float zz = sigmoidf_(Cz[r] + b_ih[100+row] + b_hh[100+row]);
          float nn = tanhf(Ci[r] + b_ih[200+row] + rr*(Ch[r] + b_hh[200+row]));
          float hnew = (1.0f-zz)*nn + zz*ho;
          if (!msk) hnew = ho;
          short hi,lo; bsplit(hnew,hi,lo);
          XcH[n*XCS+row]=hi; XcL[n*XCS+row]=lo;
        }
      }
    }
    __syncthreads();
  }

  // ---- readout: gate = sig(cat@Wg+bg), emb = gate*(h@We+be), masked sum ----
  f32x4 Cg=(f32x4)0.0f, Ce=(f32x4)0.0f;
  if (task){
    for (int ks=0;ks<5;++ks){                  // K=140: Xcat carries cat rows
      bf16x8 bh = ldB(XcH,XCS,nt,ks,lane), bl = ldB(XcL,XCS,nt,ks,lane);
      Cg = mm3(AF, 280 + jmt*5 + ks, lane, bh, bl, Cg);
    }
    for (int ks=0;ks<4;++ks){                  // K=100: We zero-pad kills rows>=100
      bf16x8 bh = ldB(XcH,XCS,nt,ks,lane), bl = ldB(XcL,XCS,nt,ks,lane);
      Ce = mm3(AF, 315 + jmt*4 + ks, lane, bh, bl, Ce);
    }
    int n = nt*16+(lane&15);
    bool msk = (sh_rowsum[n] != 0.0f);
    for (int r=0;r<4;++r){
      int row = jmt*16 + (lane>>4)*4 + r;
      float v = 0.0f;
      if (row<100){
        float gate = sigmoidf_(Cg[r] + bg[row]);
        float emb  = gate*(Ce[r] + be[row]);
        v = msk ? emb : 0.0f;
      }
      v += __shfl_xor(v, 1);                   // reduce across 16 cols
      v += __shfl_xor(v, 2);
      v += __shfl_xor(v, 4);
      v += __shfl_xor(v, 8);
      if (row<100 && (lane&15)==0) atomicAdd(&sh_ge[row], v);
    }
  }
  __syncthreads();
  // ---- out = graph_emb @ Wo + bo -------------------------------------------
  if (tid < OUT_){
    float s = bo[tid];
#pragma unroll 4
    for (int k=0;k<H_;++k) s += sh_ge[k]*Wo[k*OUT_+tid];
    out[(size_t)b*OUT_ + tid] = s;
  }
}

extern "C" void kernel_launch(void* const* d_in, const int* in_sizes, int n_in,
                              void* d_out, int out_size, void* d_ws, size_t ws_size,
                              hipStream_t stream){
  const float* nodes = (const float*)d_in[0];
  const float* edges = (const float*)d_in[1];
  const float* W_msg = (const float*)d_in[2];
  const float* W_ih  = (const float*)d_in[3];
  const float* W_hh  = (const float*)d_in[4];
  const float* b_ih  = (const float*)d_in[5];
  const float* b_hh  = (const float*)d_in[6];
  const float* Wg    = (const float*)d_in[7];
  const float* bg    = (const float*)d_in[8];
  const float* We    = (const float*)d_in[9];
  const float* be    = (const float*)d_in[10];
  const float* Wo    = (const float*)d_in[11];
  const float* bo    = (const float*)d_in[12];

  short* AF = (short*)d_ws;                 // 343*1024 shorts = 686 KB

  prep_frags<<<(NBLK*64 + 255)/256, 256, 0, stream>>>(W_msg, W_ih, W_hh, Wg, We, AF);
  mpnn_mfma<<<B_, TB, 0, stream>>>(nodes, edges, AF, b_ih, b_hh, bg, be, Wo, bo,
                                   (float*)d_out);
}

// Round 8
// 154.224 us; speedup vs baseline: 1.2317x; 1.2207x over previous
//
#include <hip/hip_runtime.h>
#include <cstddef>
#include <cstdint>

// B=256, N=32, F=40, H=M=100, EF=4, OUT=128, 3 passes.
#define B_   256
#define N_   32
#define F_   40
#define H_   100
#define OUT_ 128
#define CAP_ 8
#define TB   1024         // 16 waves/block -> 4 waves/SIMD, 1 block/CU
#define XCS  168          // Xcat row stride (shorts): k 0..159 (+8 pad), 16B-mult
#define XMS  136          // Xm / Xy row stride (shorts): k 0..127 (+8 pad)
#define NBLK 343          // A-fragment blocks in workspace

using bf16x8 = __attribute__((ext_vector_type(8))) short;   // 8 bf16 (4 VGPRs)
using f32x4  = __attribute__((ext_vector_type(4))) float;   // MFMA C/D

__device__ __forceinline__ float sigmoidf_(float x){ return 1.0f/(1.0f+__expf(-x)); }
__device__ __forceinline__ float bf2f(short s){ return __uint_as_float(((uint32_t)(uint16_t)s)<<16); }
__device__ __forceinline__ short f2bf(float x){            // round-to-nearest-even
  uint32_t u = __float_as_uint(x);
  return (short)((u + 0x7FFFu + ((u>>16)&1u))>>16);
}
__device__ __forceinline__ void bsplit(float x, short& hi, short& lo){
  hi = f2bf(x);
  lo = f2bf(x - bf2f(hi));
}

// ---------------------------------------------------------------------------
// Pre-pack every weight matrix into MFMA A-operand fragments, hi/lo bf16.
// Block table (each block = one (tile,kstep): 64 lanes x {8 hi, 8 lo} shorts):
//   [0,112)   W_msg  : t<4, jmt<7, ks<4     A[m][k]=W_msg[m, k, t]
//   [112,280) GRU    : mat<6 (ihr,ihz,ihn,hhr,hhz,hhn), jmt<7, ks<4
//   [280,315) Wg^T   : jmt<7, ks<5 (K=140)  A[j][k]=Wg[k, j]
//   [315,343) We^T   : jmt<7, ks<4          A[j][k]=We[k, j]
// Lane layout: A[m=lane&15][k=(lane>>4)*8+j]. OOR rows/cols stored as 0.
// ---------------------------------------------------------------------------
__global__ void prep_frags(const float* __restrict__ Wmsg,
                           const float* __restrict__ Wih,
                           const float* __restrict__ Whh,
                           const float* __restrict__ Wg,
                           const float* __restrict__ We,
                           short* __restrict__ AF){
  int t0 = blockIdx.x*blockDim.x + threadIdx.x;
  if (t0 >= NBLK*64) return;
  int blk = t0>>6, lane = t0&63;
  int m = lane&15, q = lane>>4;
  short* dst = AF + (size_t)blk*1024 + lane*16;
  for (int j=0;j<8;++j){
    int kl = q*8 + j;
    float v = 0.0f;
    if (blk < 112){
      int t = blk/28, rem = blk%28, jmt = rem>>2, ks = rem&3;
      int mg = jmt*16+m, k = ks*32+kl;
      if (mg<100 && k<100) v = Wmsg[(mg*100+k)*4 + t];
    } else if (blk < 280){
      int bb = blk-112, mat = bb/28, rem = bb%28, jmt = rem>>2, ks = rem&3;
      int mg = jmt*16+m, k = ks*32+kl;
      if (mg<100 && k<100)
        v = (mat<3) ? Wih[(mat*100+mg)*100+k] : Whh[((mat-3)*100+mg)*100+k];
    } else if (blk < 315){
      int bb = blk-280, jmt = bb/5, ks = bb%5;
      int mg = jmt*16+m, k = ks*32+kl;
      if (mg<100 && k<140) v = Wg[k*100+mg];
    } else {
      int bb = blk-315, jmt = bb>>2, ks = bb&3;
      int mg = jmt*16+m, k = ks*32+kl;
      if (mg<100 && k<100) v = We[k*100+mg];
    }
    short hi,lo; bsplit(v,hi,lo);
    dst[j] = hi; dst[8+j] = lo;
  }
}

// B-operand fragment from LDS [n][k] bf16: lane holds B[k=(lane>>4)*8+j][n=lane&15]
__device__ __forceinline__ bf16x8 ldB(const short* X, int stride, int nt, int ks, int lane){
  int n = nt*16 + (lane&15);
  return *(const bf16x8*)&X[n*stride + ks*32 + (lane>>4)*8];
}
// C += Ahi*Bhi + Ahi*Blo + Alo*Bhi  (split-bf16 triple product)
__device__ __forceinline__ f32x4 mm3(const short* __restrict__ AF, int blk, int lane,
                                     bf16x8 bh, bf16x8 bl, f32x4 c){
  const short* pa = AF + (size_t)blk*1024 + lane*16;
  bf16x8 ah = *(const bf16x8*)pa;
  bf16x8 al = *(const bf16x8*)(pa+8);
  c = __builtin_amdgcn_mfma_f32_16x16x32_bf16(ah, bh, c, 0,0,0);
  c = __builtin_amdgcn_mfma_f32_16x16x32_bf16(ah, bl, c, 0,0,0);
  c = __builtin_amdgcn_mfma_f32_16x16x32_bf16(al, bh, c, 0,0,0);
  return c;
}

// ---------------------------------------------------------------------------
// Fused MPNN, one block per batch, 1024 threads (16 waves).
// 14 MFMA tile-tasks (7 jm-tiles x 2 n-tiles); wave w owns task w (w<14).
// At TB=1024 the per-wave register budget is a hard 128 (64 arch + 64 acc).
// The GRU/readout GEMM loops are written with #pragma unroll 1 so the
// compiler cannot hoist dozens of A-fragment global loads (48 loads = 192
// regs in R6/R7 -> 57 MB scratch spill traffic). Keep the in-flight A-load
// window at <= 2 hi/lo pairs per phase iteration.
// ---------------------------------------------------------------------------
__global__ __launch_bounds__(TB, 4) void mpnn_mfma(
    const float* __restrict__ nodes, const float* __restrict__ edges,
    const short* __restrict__ AF,
    const float* __restrict__ b_ih, const float* __restrict__ b_hh,
    const float* __restrict__ bg, const float* __restrict__ be,
    const float* __restrict__ Wo, const float* __restrict__ bo,
    float* __restrict__ out){
  const int b = blockIdx.x;
  const int tid = threadIdx.x;
  const int lane = tid & 63;
  const int w = tid >> 6;

  __shared__ short XcH[32*XCS], XcL[32*XCS];   // cat: h(0..99) | nodes(100..139) | 0
  __shared__ short XmH[32*XMS], XmL[32*XMS];   // messages
  __shared__ short XyH[32*XMS], XyL[32*XMS];   // per-type aggregated Y_t
  __shared__ float sh_ge[H_];
  __shared__ float sh_rowsum[N_];
  __shared__ int   sh_cnt[N_];
  __shared__ int   sh_gt[N_][CAP_];            // packed (g<<2)|t
  __shared__ float sh_w[N_][CAP_];

  // ---- zero LDS ------------------------------------------------------------
  for (int i=tid;i<(32*XCS)/2;i+=TB){ ((int*)XcH)[i]=0; ((int*)XcL)[i]=0; }
  for (int i=tid;i<(32*XMS)/2;i+=TB){ ((int*)XmH)[i]=0; ((int*)XmL)[i]=0;
                                      ((int*)XyH)[i]=0; ((int*)XyL)[i]=0; }
  if (tid < H_) sh_ge[tid]=0.0f;
  if (tid < N_){ sh_cnt[tid]=0; sh_rowsum[tid]=0.0f; }
  __syncthreads();

  // ---- per-node neighbor lists + node staging ------------------------------
  for (int p=tid; p<N_*N_; p+=TB){
    int n = p>>5, g = p&31;
    const float4 ev = *(const float4*)(edges + (((size_t)b*N_+n)*N_+g)*4);
    float adj = ev.x+ev.y+ev.z+ev.w;
    if (adj != 0.0f){
      atomicAdd(&sh_rowsum[n], adj);
      float ef[4] = {ev.x,ev.y,ev.z,ev.w};
      for (int f=0; f<4; ++f)
        if (ef[f] != 0.0f){
          int s = atomicAdd(&sh_cnt[n],1);
          if (s<CAP_){ sh_gt[n][s]=(g<<2)|f; sh_w[n][s]=ef[f]; }
        }
    }
  }
  for (int p=tid; p<N_*F_; p+=TB){
    int n = p/F_, f = p%F_;
    float x = nodes[((size_t)b*N_+n)*F_ + f];
    short hi,lo; bsplit(x,hi,lo);
    XcH[n*XCS+f]=hi;      XcL[n*XCS+f]=lo;        // h init rows 0..39
    XcH[n*XCS+100+f]=hi;  XcL[n*XCS+100+f]=lo;    // cat-tail rows 100..139
  }
  __syncthreads();

  const int jmt = w>>1, nt = w&1;                 // task (w<14)
  const bool task = (w < 14);

  for (int pass=0; pass<3; ++pass){
    // ---- messages: C_msg += sum_t W_t * Y_t --------------------------------
    f32x4 Cm = (f32x4)0.0f;
#pragma unroll 1
    for (int t=0;t<4;++t){
      // build Y_t: wave-uniform n, lanes along k (packed int = 2 bf16)
      for (int it=0; it<2; ++it){
        int idx = tid + it*TB;                 // 0..2047
        int n = idx >> 6;                      // wave-uniform
        int kp = idx & 63;                     // int index: k = 2kp, 2kp+1
        int cnt = sh_cnt[n] < CAP_ ? sh_cnt[n] : CAP_;
        float s0=0.0f, s1=0.0f;
        for (int e=0;e<cnt;++e){
          int gt = sh_gt[n][e];                // wave-uniform -> scalar branch
          if ((gt&3)==t){
            int g = gt>>2; float wv = sh_w[n][e];
            int hh = ((const int*)(XcH + g*XCS))[kp];
            int ll = ((const int*)(XcL + g*XCS))[kp];
            float h0 = bf2f((short)(hh&0xffff)) + bf2f((short)(ll&0xffff));
            float h1 = bf2f((short)(hh>>16))    + bf2f((short)(ll>>16));
            s0 += wv*h0; s1 += wv*h1;
          }
        }
        short a,bs,c,d; bsplit(s0,a,bs); bsplit(s1,c,d);
        ((int*)(XyH + n*XMS))[kp] = (int)((uint16_t)a | ((uint32_t)(uint16_t)c<<16));
        ((int*)(XyL + n*XMS))[kp] = (int)((uint16_t)bs | ((uint32_t)(uint16_t)d<<16));
      }
      __syncthreads();
      if (task){
        for (int ks=0;ks<4;++ks){
          bf16x8 bh = ldB(XyH,XMS,nt,ks,lane), bl = ldB(XyL,XMS,nt,ks,lane);
          Cm = mm3(AF, (t*7+jmt)*4+ks, lane, bh, bl, Cm);
        }
      }
      __syncthreads();                         // Y_t consumed; safe to rebuild
    }
    // write messages -> Xm (rows<100)
    if (task){
      int n = nt*16+(lane&15);
      for (int r=0;r<4;++r){
        int row = jmt*16 + (lane>>4)*4 + r;
        if (row<100){
          short hi,lo; bsplit(Cm[r],hi,lo);
          XmH[n*XMS+row]=hi; XmL[n*XMS+row]=lo;
        }
      }
    }
    __syncthreads();
    // ---- GRU gate GEMMs --------------------------------------------------
    // Outer unroll-1 gate loop (g=r,z,n) caps in-flight A-loads at 2 hi/lo
    // pairs -> no register spill at the 64-arch-VGPR budget. Ca = ih_g part
    // (B = messages), Cb = hh_g part (B = hidden). g is wave-uniform so the
    // routing branches are scalar.
    f32x4 Cr=(f32x4)0.0f, Cz=(f32x4)0.0f, Ci=(f32x4)0.0f, Ch=(f32x4)0.0f;
    if (task){
#pragma unroll 1
      for (int g=0; g<3; ++g){
        f32x4 Ca=(f32x4)0.0f, Cb=(f32x4)0.0f;
        for (int ks=0;ks<4;++ks){
          bf16x8 bmh = ldB(XmH,XMS,nt,ks,lane), bml = ldB(XmL,XMS,nt,ks,lane);
          bf16x8 bhh = ldB(XcH,XCS,nt,ks,lane), bhl = ldB(XcL,XCS,nt,ks,lane);
          int base = 112 + jmt*4 + ks;
          Ca = mm3(AF, base + g*28,       lane, bmh, bml, Ca);  // ih_g
          Cb = mm3(AF, base + (g+3)*28,   lane, bhh, bhl, Cb);  // hh_g
        }
        if (g==0)      Cr = Ca + Cb;
        else if (g==1) Cz = Ca + Cb;
        else         { Ci = Ca; Ch = Cb; }
      }
    }
    __syncthreads();                           // all Xc/Xm reads done
    // ---- GRU elementwise: update h rows of Xcat in place -------------------
    if (task){
      int n = nt*16+(lane&15);
      bool msk = (sh_rowsum[n] != 0.0f);
      for (int r=0;r<4;++r){
        int row = jmt*16 + (lane>>4)*4 + r;
        if (row<100){
          float ho = bf2f(XcH[n*XCS+row]) + bf2f(XcL[n*XCS+row]);
          float rr = sigmoidf_(Cr[r] + b_ih[row]     + b_hh[row]);
          float zz = sigmoidf_(Cz[r] + b_ih[100+row] + b_hh[100+row]);
          float nn = tanhf(Ci[r] + b_ih[200+row] + rr*(Ch[r] + b_hh[200+row]));
          float hnew = (1.0f-zz)*nn + zz*ho;
          if (!msk) hnew = ho;
          short hi,lo; bsplit(hnew,hi,lo);
          XcH[n*XCS+row]=hi; XcL[n*XCS+row]=lo;
        }
      }
    }
    __syncthreads();
  }

  // ---- readout: gate = sig(cat@Wg+bg), emb = gate*(h@We+be), masked sum ----
  f32x4 Cg=(f32x4)0.0f, Ce=(f32x4)0.0f;
  if (task){
#pragma unroll 1
    for (int ks=0;ks<5;++ks){                  // K=140: Xcat carries cat rows
      bf16x8 bh = ldB(XcH,XCS,nt,ks,lane), bl = ldB(XcL,XCS,nt,ks,lane);
      Cg = mm3(AF, 280 + jmt*5 + ks, lane, bh, bl, Cg);
    }
#pragma unroll 1
    for (int ks=0;ks<4;++ks){                  // K=100: We zero-pad kills rows>=100
      bf16x8 bh = ldB(XcH,XCS,nt,ks,lane), bl = ldB(XcL,XCS,nt,ks,lane);
      Ce = mm3(AF, 315 + jmt*4 + ks, lane, bh, bl, Ce);
    }
    int n = nt*16+(lane&15);
    bool msk = (sh_rowsum[n] != 0.0f);
    for (int r=0;r<4;++r){
      int row = jmt*16 + (lane>>4)*4 + r;
      float v = 0.0f;
      if (row<100){
        float gate = sigmoidf_(Cg[r] + bg[row]);
        float emb  = gate*(Ce[r] + be[row]);
        v = msk ? emb : 0.0f;
      }
      v += __shfl_xor(v, 1);                   // reduce across 16 cols
      v += __shfl_xor(v, 2);
      v += __shfl_xor(v, 4);
      v += __shfl_xor(v, 8);
      if (row<100 && (lane&15)==0) atomicAdd(&sh_ge[row], v);
    }
  }
  __syncthreads();
  // ---- out = graph_emb @ Wo + bo -------------------------------------------
  if (tid < OUT_){
    float s = bo[tid];
#pragma unroll 4
    for (int k=0;k<H_;++k) s += sh_ge[k]*Wo[k*OUT_+tid];
    out[(size_t)b*OUT_ + tid] = s;
  }
}

extern "C" void kernel_launch(void* const* d_in, const int* in_sizes, int n_in,
                              void* d_out, int out_size, void* d_ws, size_t ws_size,
                              hipStream_t stream){
  const float* nodes = (const float*)d_in[0];
  const float* edges = (const float*)d_in[1];
  const float* W_msg = (const float*)d_in[2];
  const float* W_ih  = (const float*)d_in[3];
  const float* W_hh  = (const float*)d_in[4];
  const float* b_ih  = (const float*)d_in[5];
  const float* b_hh  = (const float*)d_in[6];
  const float* Wg    = (const float*)d_in[7];
  const float* bg    = (const float*)d_in[8];
  const float* We    = (const float*)d_in[9];
  const float* be    = (const float*)d_in[10];
  const float* Wo    = (const float*)d_in[11];
  const float* bo    = (const float*)d_in[12];

  short* AF = (short*)d_ws;                 // 343*1024 shorts = 686 KB

  prep_frags<<<(NBLK*64 + 255)/256, 256, 0, stream>>>(W_msg, W_ih, W_hh, Wg, We, AF);
  mpnn_mfma<<<B_, TB, 0, stream>>>(nodes, edges, AF, b_ih, b_hh, bg, be, Wo, bo,
                                   (float*)d_out);
}

// Round 9
// 149.019 us; speedup vs baseline: 1.2747x; 1.0349x over previous
//
#include <hip/hip_runtime.h>
#include <cstddef>
#include <cstdint>

// B=256, N=32, F=40, H=M=100, EF=4, OUT=128, 3 passes.
#define B_   256
#define N_   32
#define F_   40
#define H_   100
#define OUT_ 128
#define CAP_ 8
#define TB   1024         // 16 waves/block -> 4 waves/SIMD, 1 block/CU
#define XCS  168          // Xcat row stride (shorts): k 0..159 (+8 pad), 16B-mult
#define XMS  136          // Xm / Xy row stride (shorts): k 0..127 (+8 pad)
#define NBLK 343          // A-fragment blocks in workspace

using bf16x8 = __attribute__((ext_vector_type(8))) short;   // 8 bf16 (4 VGPRs)
using f32x4  = __attribute__((ext_vector_type(4))) float;   // MFMA C/D

__device__ __forceinline__ float sigmoidf_(float x){ return 1.0f/(1.0f+__expf(-x)); }
__device__ __forceinline__ float bf2f(short s){ return __uint_as_float(((uint32_t)(uint16_t)s)<<16); }
__device__ __forceinline__ short f2bf(float x){            // round-to-nearest-even
  uint32_t u = __float_as_uint(x);
  return (short)((u + 0x7FFFu + ((u>>16)&1u))>>16);
}
__device__ __forceinline__ void bsplit(float x, short& hi, short& lo){
  hi = f2bf(x);
  lo = f2bf(x - bf2f(hi));
}

// ---------------------------------------------------------------------------
// Pre-pack every weight matrix into MFMA A-operand fragments, hi/lo bf16.
// Block table (each block = one (tile,kstep): 64 lanes x {8 hi, 8 lo} shorts):
//   [0,112)   W_msg  : t<4, jmt<7, ks<4     A[m][k]=W_msg[m, k, t]
//   [112,280) GRU    : mat<6 (ihr,ihz,ihn,hhr,hhz,hhn), jmt<7, ks<4
//   [280,315) Wg^T   : jmt<7, ks<5 (K=140)  A[j][k]=Wg[k, j]
//   [315,343) We^T   : jmt<7, ks<4          A[j][k]=We[k, j]
// Lane layout: A[m=lane&15][k=(lane>>4)*8+j]. OOR rows/cols stored as 0.
// ---------------------------------------------------------------------------
__global__ void prep_frags(const float* __restrict__ Wmsg,
                           const float* __restrict__ Wih,
                           const float* __restrict__ Whh,
                           const float* __restrict__ Wg,
                           const float* __restrict__ We,
                           short* __restrict__ AF){
  int t0 = blockIdx.x*blockDim.x + threadIdx.x;
  if (t0 >= NBLK*64) return;
  int blk = t0>>6, lane = t0&63;
  int m = lane&15, q = lane>>4;
  short* dst = AF + (size_t)blk*1024 + lane*16;
  for (int j=0;j<8;++j){
    int kl = q*8 + j;
    float v = 0.0f;
    if (blk < 112){
      int t = blk/28, rem = blk%28, jmt = rem>>2, ks = rem&3;
      int mg = jmt*16+m, k = ks*32+kl;
      if (mg<100 && k<100) v = Wmsg[(mg*100+k)*4 + t];
    } else if (blk < 280){
      int bb = blk-112, mat = bb/28, rem = bb%28, jmt = rem>>2, ks = rem&3;
      int mg = jmt*16+m, k = ks*32+kl;
      if (mg<100 && k<100)
        v = (mat<3) ? Wih[(mat*100+mg)*100+k] : Whh[((mat-3)*100+mg)*100+k];
    } else if (blk < 315){
      int bb = blk-280, jmt = bb/5, ks = bb%5;
      int mg = jmt*16+m, k = ks*32+kl;
      if (mg<100 && k<140) v = Wg[k*100+mg];
    } else {
      int bb = blk-315, jmt = bb>>2, ks = bb&3;
      int mg = jmt*16+m, k = ks*32+kl;
      if (mg<100 && k<100) v = We[k*100+mg];
    }
    short hi,lo; bsplit(v,hi,lo);
    dst[j] = hi; dst[8+j] = lo;
  }
}

// B-operand fragment from LDS [n][k] bf16: lane holds B[k=(lane>>4)*8+j][n=lane&15]
__device__ __forceinline__ bf16x8 ldB(const short* X, int stride, int nt, int ks, int lane){
  int n = nt*16 + (lane&15);
  return *(const bf16x8*)&X[n*stride + ks*32 + (lane>>4)*8];
}
// C += Ahi*Bhi + Ahi*Blo + Alo*Bhi  (split-bf16 triple product)
__device__ __forceinline__ f32x4 mm3(const short* __restrict__ AF, int blk, int lane,
                                     bf16x8 bh, bf16x8 bl, f32x4 c){
  const short* pa = AF + (size_t)blk*1024 + lane*16;
  bf16x8 ah = *(const bf16x8*)pa;
  bf16x8 al = *(const bf16x8*)(pa+8);
  c = __builtin_amdgcn_mfma_f32_16x16x32_bf16(ah, bh, c, 0,0,0);
  c = __builtin_amdgcn_mfma_f32_16x16x32_bf16(ah, bl, c, 0,0,0);
  c = __builtin_amdgcn_mfma_f32_16x16x32_bf16(al, bh, c, 0,0,0);
  return c;
}

// ---------------------------------------------------------------------------
// Fused MPNN, one block per batch, 1024 threads (16 waves).
// 14 MFMA tile-tasks (7 jm-tiles x 2 n-tiles); wave w owns task w (w<14).
// At TB=1024 the per-wave register budget is a hard 128 (64 arch + 64 acc).
// EVERY multi-mm3 loop carries #pragma unroll 1: unrolled ks-loops hoist
// dozens of A-fragment loads past the 64-arch-VGPR budget and spill to
// scratch (R6/R7: 57 MB, R8 after gate-loop fix: 22.6 MB from the still-
// unrolled ks loops). Keep the in-flight window at <=2 A hi/lo pairs.
// ---------------------------------------------------------------------------
__global__ __launch_bounds__(TB, 4) void mpnn_mfma(
    const float* __restrict__ nodes, const float* __restrict__ edges,
    const short* __restrict__ AF,
    const float* __restrict__ b_ih, const float* __restrict__ b_hh,
    const float* __restrict__ bg, const float* __restrict__ be,
    const float* __restrict__ Wo, const float* __restrict__ bo,
    float* __restrict__ out){
  const int b = blockIdx.x;
  const int tid = threadIdx.x;
  const int lane = tid & 63;
  const int w = tid >> 6;

  __shared__ short XcH[32*XCS], XcL[32*XCS];   // cat: h(0..99) | nodes(100..139) | 0
  __shared__ short XmH[32*XMS], XmL[32*XMS];   // messages
  __shared__ short XyH[32*XMS], XyL[32*XMS];   // per-type aggregated Y_t
  __shared__ float sh_ge[H_];
  __shared__ float sh_rowsum[N_];
  __shared__ int   sh_cnt[N_];
  __shared__ int   sh_gt[N_][CAP_];            // packed (g<<2)|t
  __shared__ float sh_w[N_][CAP_];

  // ---- zero LDS ------------------------------------------------------------
  for (int i=tid;i<(32*XCS)/2;i+=TB){ ((int*)XcH)[i]=0; ((int*)XcL)[i]=0; }
  for (int i=tid;i<(32*XMS)/2;i+=TB){ ((int*)XmH)[i]=0; ((int*)XmL)[i]=0;
                                      ((int*)XyH)[i]=0; ((int*)XyL)[i]=0; }
  if (tid < H_) sh_ge[tid]=0.0f;
  if (tid < N_){ sh_cnt[tid]=0; sh_rowsum[tid]=0.0f; }
  __syncthreads();

  // ---- per-node neighbor lists + node staging ------------------------------
  for (int p=tid; p<N_*N_; p+=TB){
    int n = p>>5, g = p&31;
    const float4 ev = *(const float4*)(edges + (((size_t)b*N_+n)*N_+g)*4);
    float adj = ev.x+ev.y+ev.z+ev.w;
    if (adj != 0.0f){
      atomicAdd(&sh_rowsum[n], adj);
      float ef[4] = {ev.x,ev.y,ev.z,ev.w};
      for (int f=0; f<4; ++f)
        if (ef[f] != 0.0f){
          int s = atomicAdd(&sh_cnt[n],1);
          if (s<CAP_){ sh_gt[n][s]=(g<<2)|f; sh_w[n][s]=ef[f]; }
        }
    }
  }
  for (int p=tid; p<N_*F_; p+=TB){
    int n = p/F_, f = p%F_;
    float x = nodes[((size_t)b*N_+n)*F_ + f];
    short hi,lo; bsplit(x,hi,lo);
    XcH[n*XCS+f]=hi;      XcL[n*XCS+f]=lo;        // h init rows 0..39
    XcH[n*XCS+100+f]=hi;  XcL[n*XCS+100+f]=lo;    // cat-tail rows 100..139
  }
  __syncthreads();

  const int jmt = w>>1, nt = w&1;                 // task (w<14)
  const bool task = (w < 14);

  for (int pass=0; pass<3; ++pass){
    // ---- messages: C_msg += sum_t W_t * Y_t --------------------------------
    f32x4 Cm = (f32x4)0.0f;
#pragma unroll 1
    for (int t=0;t<4;++t){
      // build Y_t: wave-uniform n, lanes along k (packed int = 2 bf16)
      for (int it=0; it<2; ++it){
        int idx = tid + it*TB;                 // 0..2047
        int n = idx >> 6;                      // wave-uniform
        int kp = idx & 63;                     // int index: k = 2kp, 2kp+1
        int cnt = sh_cnt[n] < CAP_ ? sh_cnt[n] : CAP_;
        float s0=0.0f, s1=0.0f;
        for (int e=0;e<cnt;++e){
          int gt = sh_gt[n][e];                // wave-uniform -> scalar branch
          if ((gt&3)==t){
            int g = gt>>2; float wv = sh_w[n][e];
            int hh = ((const int*)(XcH + g*XCS))[kp];
            int ll = ((const int*)(XcL + g*XCS))[kp];
            float h0 = bf2f((short)(hh&0xffff)) + bf2f((short)(ll&0xffff));
            float h1 = bf2f((short)(hh>>16))    + bf2f((short)(ll>>16));
            s0 += wv*h0; s1 += wv*h1;
          }
        }
        short a,bs,c,d; bsplit(s0,a,bs); bsplit(s1,c,d);
        ((int*)(XyH + n*XMS))[kp] = (int)((uint16_t)a | ((uint32_t)(uint16_t)c<<16));
        ((int*)(XyL + n*XMS))[kp] = (int)((uint16_t)bs | ((uint32_t)(uint16_t)d<<16));
      }
      __syncthreads();
      if (task){
#pragma unroll 1
        for (int ks=0;ks<4;++ks){
          bf16x8 bh = ldB(XyH,XMS,nt,ks,lane), bl = ldB(XyL,XMS,nt,ks,lane);
          Cm = mm3(AF, (t*7+jmt)*4+ks, lane, bh, bl, Cm);
        }
      }
      __syncthreads();                         // Y_t consumed; safe to rebuild
    }
    // write messages -> Xm (rows<100)
    if (task){
      int n = nt*16+(lane&15);
      for (int r=0;r<4;++r){
        int row = jmt*16 + (lane>>4)*4 + r;
        if (row<100){
          short hi,lo; bsplit(Cm[r],hi,lo);
          XmH[n*XMS+row]=hi; XmL[n*XMS+row]=lo;
        }
      }
    }
    __syncthreads();
    // ---- GRU gate GEMMs --------------------------------------------------
    // Outer unroll-1 gate loop (g=r,z,n), inner unroll-1 ks loop: caps
    // in-flight A-loads at 2 hi/lo pairs -> no spill at 64 arch VGPRs.
    f32x4 Cr=(f32x4)0.0f, Cz=(f32x4)0.0f, Ci=(f32x4)0.0f, Ch=(f32x4)0.0f;
    if (task){
#pragma unroll 1
      for (int g=0; g<3; ++g){
        f32x4 Ca=(f32x4)0.0f, Cb=(f32x4)0.0f;
#pragma unroll 1
        for (int ks=0;ks<4;++ks){
          bf16x8 bmh = ldB(XmH,XMS,nt,ks,lane), bml = ldB(XmL,XMS,nt,ks,lane);
          bf16x8 bhh = ldB(XcH,XCS,nt,ks,lane), bhl = ldB(XcL,XCS,nt,ks,lane);
          int base = 112 + jmt*4 + ks;
          Ca = mm3(AF, base + g*28,       lane, bmh, bml, Ca);  // ih_g
          Cb = mm3(AF, base + (g+3)*28,   lane, bhh, bhl, Cb);  // hh_g
        }
        if (g==0)      Cr = Ca + Cb;
        else if (g==1) Cz = Ca + Cb;
        else         { Ci = Ca; Ch = Cb; }
      }
    }
    __syncthreads();                           // all Xc/Xm reads done
    // ---- GRU elementwise: update h rows of Xcat in place -------------------
    if (task){
      int n = nt*16+(lane&15);
      bool msk = (sh_rowsum[n] != 0.0f);
      for (int r=0;r<4;++r){
        int row = jmt*16 + (lane>>4)*4 + r;
        if (row<100){
          float ho = bf2f(XcH[n*XCS+row]) + bf2f(XcL[n*XCS+row]);
          float rr = sigmoidf_(Cr[r] + b_ih[row]     + b_hh[row]);
          float zz = sigmoidf_(Cz[r] + b_ih[100+row] + b_hh[100+row]);
          float nn = tanhf(Ci[r] + b_ih[200+row] + rr*(Ch[r] + b_hh[200+row]));
          float hnew = (1.0f-zz)*nn + zz*ho;
          if (!msk) hnew = ho;
          short hi,lo; bsplit(hnew,hi,lo);
          XcH[n*XCS+row]=hi; XcL[n*XCS+row]=lo;
        }
      }
    }
    __syncthreads();
  }

  // ---- readout: gate = sig(cat@Wg+bg), emb = gate*(h@We+be), masked sum ----
  f32x4 Cg=(f32x4)0.0f, Ce=(f32x4)0.0f;
  if (task){
#pragma unroll 1
    for (int ks=0;ks<5;++ks){                  // K=140: Xcat carries cat rows
      bf16x8 bh = ldB(XcH,XCS,nt,ks,lane), bl = ldB(XcL,XCS,nt,ks,lane);
      Cg = mm3(AF, 280 + jmt*5 + ks, lane, bh, bl, Cg);
    }
#pragma unroll 1
    for (int ks=0;ks<4;++ks){                  // K=100: We zero-pad kills rows>=100
      bf16x8 bh = ldB(XcH,XCS,nt,ks,lane), bl = ldB(XcL,XCS,nt,ks,lane);
      Ce = mm3(AF, 315 + jmt*4 + ks, lane, bh, bl, Ce);
    }
    int n = nt*16+(lane&15);
    bool msk = (sh_rowsum[n] != 0.0f);
    for (int r=0;r<4;++r){
      int row = jmt*16 + (lane>>4)*4 + r;
      float v = 0.0f;
      if (row<100){
        float gate = sigmoidf_(Cg[r] + bg[row]);
        float emb  = gate*(Ce[r] + be[row]);
        v = msk ? emb : 0.0f;
      }
      v += __shfl_xor(v, 1);                   // reduce across 16 cols
      v += __shfl_xor(v, 2);
      v += __shfl_xor(v, 4);
      v += __shfl_xor(v, 8);
      if (row<100 && (lane&15)==0) atomicAdd(&sh_ge[row], v);
    }
  }
  __syncthreads();
  // ---- out = graph_emb @ Wo + bo -------------------------------------------
  if (tid < OUT_){
    float s = bo[tid];
#pragma unroll 4
    for (int k=0;k<H_;++k) s += sh_ge[k]*Wo[k*OUT_+tid];
    out[(size_t)b*OUT_ + tid] = s;
  }
}

extern "C" void kernel_launch(void* const* d_in, const int* in_sizes, int n_in,
                              void* d_out, int out_size, void* d_ws, size_t ws_size,
                              hipStream_t stream){
  const float* nodes = (const float*)d_in[0];
  const float* edges = (const float*)d_in[1];
  const float* W_msg = (const float*)d_in[2];
  const float* W_ih  = (const float*)d_in[3];
  const float* W_hh  = (const float*)d_in[4];
  const float* b_ih  = (const float*)d_in[5];
  const float* b_hh  = (const float*)d_in[6];
  const float* Wg    = (const float*)d_in[7];
  const float* bg    = (const float*)d_in[8];
  const float* We    = (const float*)d_in[9];
  const float* be    = (const float*)d_in[10];
  const float* Wo    = (const float*)d_in[11];
  const float* bo    = (const float*)d_in[12];

  short* AF = (short*)d_ws;                 // 343*1024 shorts = 686 KB

  prep_frags<<<(NBLK*64 + 255)/256, 256, 0, stream>>>(W_msg, W_ih, W_hh, Wg, We, AF);
  mpnn_mfma<<<B_, TB, 0, stream>>>(nodes, edges, AF, b_ih, b_hh, bg, be, Wo, bo,
                                   (float*)d_out);
}

// Round 10
// 139.567 us; speedup vs baseline: 1.3610x; 1.0677x over previous
//
#include <hip/hip_runtime.h>
#include <cstddef>
#include <cstdint>

// B=256, N=32, F=40, H=M=100, EF=4, OUT=128, 3 passes.
#define B_   256
#define N_   32
#define F_   40
#define H_   100
#define OUT_ 128
#define CAP_ 8
#define TB   1024         // 16 waves/block -> 4 waves/SIMD, 1 block/CU
#define XCS  168          // Xcat row stride (shorts): k 0..159 (+8 pad), 16B-mult
#define XMS  136          // Xm / Xy row stride (shorts): k 0..127 (+8 pad)
#define NBLK 343          // A-fragment blocks in workspace

using bf16x8 = __attribute__((ext_vector_type(8))) short;   // 8 bf16 (4 VGPRs)
using f32x4  = __attribute__((ext_vector_type(4))) float;   // MFMA C/D

__device__ __forceinline__ float sigmoidf_(float x){ return 1.0f/(1.0f+__expf(-x)); }
__device__ __forceinline__ float bf2f(short s){ return __uint_as_float(((uint32_t)(uint16_t)s)<<16); }
__device__ __forceinline__ short f2bf(float x){            // round-to-nearest-even
  uint32_t u = __float_as_uint(x);
  return (short)((u + 0x7FFFu + ((u>>16)&1u))>>16);
}
__device__ __forceinline__ void bsplit(float x, short& hi, short& lo){
  hi = f2bf(x);
  lo = f2bf(x - bf2f(hi));
}

// ---------------------------------------------------------------------------
// Pre-pack every weight matrix into MFMA A-operand fragments, hi/lo bf16.
// Block table (each block = one (tile,kstep): 64 lanes x {8 hi, 8 lo} shorts):
//   [0,112)   W_msg  : t<4, jmt<7, ks<4     A[m][k]=W_msg[m, k, t]
//   [112,280) GRU    : mat<6 (ihr,ihz,ihn,hhr,hhz,hhn), jmt<7, ks<4
//   [280,315) Wg^T   : jmt<7, ks<5 (K=140)  A[j][k]=Wg[k, j]
//   [315,343) We^T   : jmt<7, ks<4          A[j][k]=We[k, j]
// Lane layout: A[m=lane&15][k=(lane>>4)*8+j]. OOR rows/cols stored as 0.
// ---------------------------------------------------------------------------
__global__ void prep_frags(const float* __restrict__ Wmsg,
                           const float* __restrict__ Wih,
                           const float* __restrict__ Whh,
                           const float* __restrict__ Wg,
                           const float* __restrict__ We,
                           short* __restrict__ AF){
  int t0 = blockIdx.x*blockDim.x + threadIdx.x;
  if (t0 >= NBLK*64) return;
  int blk = t0>>6, lane = t0&63;
  int m = lane&15, q = lane>>4;
  short* dst = AF + (size_t)blk*1024 + lane*16;
  for (int j=0;j<8;++j){
    int kl = q*8 + j;
    float v = 0.0f;
    if (blk < 112){
      int t = blk/28, rem = blk%28, jmt = rem>>2, ks = rem&3;
      int mg = jmt*16+m, k = ks*32+kl;
      if (mg<100 && k<100) v = Wmsg[(mg*100+k)*4 + t];
    } else if (blk < 280){
      int bb = blk-112, mat = bb/28, rem = bb%28, jmt = rem>>2, ks = rem&3;
      int mg = jmt*16+m, k = ks*32+kl;
      if (mg<100 && k<100)
        v = (mat<3) ? Wih[(mat*100+mg)*100+k] : Whh[((mat-3)*100+mg)*100+k];
    } else if (blk < 315){
      int bb = blk-280, jmt = bb/5, ks = bb%5;
      int mg = jmt*16+m, k = ks*32+kl;
      if (mg<100 && k<140) v = Wg[k*100+mg];
    } else {
      int bb = blk-315, jmt = bb>>2, ks = bb&3;
      int mg = jmt*16+m, k = ks*32+kl;
      if (mg<100 && k<100) v = We[k*100+mg];
    }
    short hi,lo; bsplit(v,hi,lo);
    dst[j] = hi; dst[8+j] = lo;
  }
}

// B-operand fragment from LDS [n][k] bf16: lane holds B[k=(lane>>4)*8+j][n=lane&15]
__device__ __forceinline__ bf16x8 ldB(const short* X, int stride, int nt, int ks, int lane){
  int n = nt*16 + (lane&15);
  return *(const bf16x8*)&X[n*stride + ks*32 + (lane>>4)*8];
}
// C += Ahi*Bhi + Ahi*Blo + Alo*Bhi  (split-bf16 triple product)
__device__ __forceinline__ f32x4 mm3(const short* __restrict__ AF, int blk, int lane,
                                     bf16x8 bh, bf16x8 bl, f32x4 c){
  const short* pa = AF + (size_t)blk*1024 + lane*16;
  bf16x8 ah = *(const bf16x8*)pa;
  bf16x8 al = *(const bf16x8*)(pa+8);
  c = __builtin_amdgcn_mfma_f32_16x16x32_bf16(ah, bh, c, 0,0,0);
  c = __builtin_amdgcn_mfma_f32_16x16x32_bf16(ah, bl, c, 0,0,0);
  c = __builtin_amdgcn_mfma_f32_16x16x32_bf16(al, bh, c, 0,0,0);
  return c;
}

// ---------------------------------------------------------------------------
// Fused MPNN, one block per batch, 1024 threads (16 waves).
// 14 MFMA tile-tasks (7 jm-tiles x 2 n-tiles); wave w owns task w (w<14).
// Phase-minimized: all four Y_t built in ONE sweep into Xy[4] (each edge has
// exactly one type), so the messages section is build -> bar -> 16 mm3 +
// Xm-write -> bar (was 8 barriers/pass, now 2). 4 barriers per pass total.
// All multi-mm3 loops carry #pragma unroll 1 (spill guard: R6-R9 showed
// unrolled ks-loops hoist A-loads past the 64-arch-VGPR cap -> scratch).
// ---------------------------------------------------------------------------
__global__ __launch_bounds__(TB, 4) void mpnn_mfma(
    const float* __restrict__ nodes, const float* __restrict__ edges,
    const short* __restrict__ AF,
    const float* __restrict__ b_ih, const float* __restrict__ b_hh,
    const float* __restrict__ bg, const float* __restrict__ be,
    const float* __restrict__ Wo, const float* __restrict__ bo,
    float* __restrict__ out){
  const int b = blockIdx.x;
  const int tid = threadIdx.x;
  const int lane = tid & 63;
  const int w = tid >> 6;

  __shared__ short XcH[32*XCS], XcL[32*XCS];      // cat: h | nodes(100..139) | 0
  __shared__ short XmH[32*XMS], XmL[32*XMS];      // messages
  __shared__ short XyH[4][32*XMS], XyL[4][32*XMS];// per-type aggregated Y_t
  __shared__ float sh_ge[H_];
  __shared__ float sh_part[4][OUT_];              // Wo-tail partials
  __shared__ float sh_rowsum[N_];
  __shared__ int   sh_cnt[N_];
  __shared__ int   sh_gt[N_][CAP_];               // packed (g<<2)|t
  __shared__ float sh_w[N_][CAP_];

  // ---- zero LDS (Xc: rows>=140 must stay 0; Xm: rows>=100 must stay 0;
  //      Xy needs no init -- fully rewritten every pass before reads) --------
  for (int i=tid;i<(32*XCS)/2;i+=TB){ ((int*)XcH)[i]=0; ((int*)XcL)[i]=0; }
  for (int i=tid;i<(32*XMS)/2;i+=TB){ ((int*)XmH)[i]=0; ((int*)XmL)[i]=0; }
  if (tid < H_) sh_ge[tid]=0.0f;
  if (tid < N_){ sh_cnt[tid]=0; sh_rowsum[tid]=0.0f; }
  __syncthreads();

  // ---- per-node neighbor lists + node staging ------------------------------
  for (int p=tid; p<N_*N_; p+=TB){
    int n = p>>5, g = p&31;
    const float4 ev = *(const float4*)(edges + (((size_t)b*N_+n)*N_+g)*4);
    float adj = ev.x+ev.y+ev.z+ev.w;
    if (adj != 0.0f){
      atomicAdd(&sh_rowsum[n], adj);
      float ef[4] = {ev.x,ev.y,ev.z,ev.w};
      for (int f=0; f<4; ++f)
        if (ef[f] != 0.0f){
          int s = atomicAdd(&sh_cnt[n],1);
          if (s<CAP_){ sh_gt[n][s]=(g<<2)|f; sh_w[n][s]=ef[f]; }
        }
    }
  }
  for (int p=tid; p<N_*F_; p+=TB){
    int n = p/F_, f = p%F_;
    float x = nodes[((size_t)b*N_+n)*F_ + f];
    short hi,lo; bsplit(x,hi,lo);
    XcH[n*XCS+f]=hi;      XcL[n*XCS+f]=lo;        // h init rows 0..39
    XcH[n*XCS+100+f]=hi;  XcL[n*XCS+100+f]=lo;    // cat-tail rows 100..139
  }
  __syncthreads();

  const int jmt = w>>1, nt = w&1;                 // task (w<14)
  const bool task = (w < 14);

  for (int pass=0; pass<3; ++pass){
    // ---- build ALL Y_t in one sweep: n wave-uniform, lanes along k ---------
    for (int it=0; it<2; ++it){
      int idx = tid + it*TB;                   // 0..2047
      int n = idx >> 6;                        // wave-uniform
      int kp = idx & 63;                       // int index: k = 2kp, 2kp+1
      int cnt = sh_cnt[n] < CAP_ ? sh_cnt[n] : CAP_;
      float s0[4]={0,0,0,0}, s1[4]={0,0,0,0};
      for (int e=0;e<cnt;++e){
        int gt = sh_gt[n][e];                  // wave-uniform -> scalar branch
        int g = gt>>2; float wv = sh_w[n][e];
        int hh = ((const int*)(XcH + g*XCS))[kp];
        int ll = ((const int*)(XcL + g*XCS))[kp];
        float h0 = bf2f((short)(hh&0xffff)) + bf2f((short)(ll&0xffff));
        float h1 = bf2f((short)(hh>>16))    + bf2f((short)(ll>>16));
        int t = gt&3;                          // wave-uniform scatter
        if (t==0)      { s0[0]+=wv*h0; s1[0]+=wv*h1; }
        else if (t==1) { s0[1]+=wv*h0; s1[1]+=wv*h1; }
        else if (t==2) { s0[2]+=wv*h0; s1[2]+=wv*h1; }
        else           { s0[3]+=wv*h0; s1[3]+=wv*h1; }
      }
#pragma unroll
      for (int t=0;t<4;++t){
        short a,b2,c,d; bsplit(s0[t],a,b2); bsplit(s1[t],c,d);
        ((int*)(XyH[t] + n*XMS))[kp] = (int)((uint16_t)a  | ((uint32_t)(uint16_t)c<<16));
        ((int*)(XyL[t] + n*XMS))[kp] = (int)((uint16_t)b2 | ((uint32_t)(uint16_t)d<<16));
      }
    }
    __syncthreads();
    // ---- messages: C_msg = sum_t W_t * Y_t, then write Xm ------------------
    if (task){
      f32x4 Cm = (f32x4)0.0f;
#pragma unroll 1
      for (int i=0;i<16;++i){
        int t = i>>2, ks = i&3;
        bf16x8 bh = ldB(XyH[t],XMS,nt,ks,lane), bl = ldB(XyL[t],XMS,nt,ks,lane);
        Cm = mm3(AF, (t*7+jmt)*4+ks, lane, bh, bl, Cm);
      }
      int n = nt*16+(lane&15);                 // Xm write: disjoint from Xy
      for (int r=0;r<4;++r){
        int row = jmt*16 + (lane>>4)*4 + r;
        if (row<100){
          short hi,lo; bsplit(Cm[r],hi,lo);
          XmH[n*XMS+row]=hi; XmL[n*XMS+row]=lo;
        }
      }
    }
    __syncthreads();
    // ---- GRU gate GEMMs (outer unroll-1 gate loop, inner unroll-1 ks) ------
    f32x4 Cr=(f32x4)0.0f, Cz=(f32x4)0.0f, Ci=(f32x4)0.0f, Ch=(f32x4)0.0f;
    if (task){
#pragma unroll 1
      for (int g=0; g<3; ++g){
        f32x4 Ca=(f32x4)0.0f, Cb=(f32x4)0.0f;
#pragma unroll 1
        for (int ks=0;ks<4;++ks){
          bf16x8 bmh = ldB(XmH,XMS,nt,ks,lane), bml = ldB(XmL,XMS,nt,ks,lane);
          bf16x8 bhh = ldB(XcH,XCS,nt,ks,lane), bhl = ldB(XcL,XCS,nt,ks,lane);
          int base = 112 + jmt*4 + ks;
          Ca = mm3(AF, base + g*28,     lane, bmh, bml, Ca);  // ih_g
          Cb = mm3(AF, base + (g+3)*28, lane, bhh, bhl, Cb);  // hh_g
        }
        if (g==0)      Cr = Ca + Cb;
        else if (g==1) Cz = Ca + Cb;
        else         { Ci = Ca; Ch = Cb; }
      }
    }
    __syncthreads();                           // all Xc/Xm reads done
    // ---- GRU elementwise: update h rows of Xcat in place -------------------
    if (task){
      int n = nt*16+(lane&15);
      bool msk = (sh_rowsum[n] != 0.0f);
      for (int r=0;r<4;++r){
        int row = jmt*16 + (lane>>4)*4 + r;
        if (row<100){
          float ho = bf2f(XcH[n*XCS+row]) + bf2f(XcL[n*XCS+row]);
          float rr = sigmoidf_(Cr[r] + b_ih[row]     + b_hh[row]);
          float zz = sigmoidf_(Cz[r] + b_ih[100+row] + b_hh[100+row]);
          float nn = tanhf(Ci[r] + b_ih[200+row] + rr*(Ch[r] + b_hh[200+row]));
          float hnew = (1.0f-zz)*nn + zz*ho;
          if (!msk) hnew = ho;
          short hi,lo; bsplit(hnew,hi,lo);
          XcH[n*XCS+row]=hi; XcL[n*XCS+row]=lo;
        }
      }
    }
    __syncthreads();
  }

  // ---- readout: gate = sig(cat@Wg+bg), emb = gate*(h@We+be), masked sum ----
  f32x4 Cg=(f32x4)0.0f, Ce=(f32x4)0.0f;
  if (task){
#pragma unroll 1
    for (int ks=0;ks<5;++ks){                  // K=140: Xcat carries cat rows
      bf16x8 bh = ldB(XcH,XCS,nt,ks,lane), bl = ldB(XcL,XCS,nt,ks,lane);
      Cg = mm3(AF, 280 + jmt*5 + ks, lane, bh, bl, Cg);
    }
#pragma unroll 1
    for (int ks=0;ks<4;++ks){                  // K=100: We zero-pad kills rows>=100
      bf16x8 bh = ldB(XcH,XCS,nt,ks,lane), bl = ldB(XcL,XCS,nt,ks,lane);
      Ce = mm3(AF, 315 + jmt*4 + ks, lane, bh, bl, Ce);
    }
    int n = nt*16+(lane&15);
    bool msk = (sh_rowsum[n] != 0.0f);
    for (int r=0;r<4;++r){
      int row = jmt*16 + (lane>>4)*4 + r;
      float v = 0.0f;
      if (row<100){
        float gate = sigmoidf_(Cg[r] + bg[row]);
        float emb  = gate*(Ce[r] + be[row]);
        v = msk ? emb : 0.0f;
      }
      v += __shfl_xor(v, 1);                   // reduce across 16 cols
      v += __shfl_xor(v, 2);
      v += __shfl_xor(v, 4);
      v += __shfl_xor(v, 8);
      if (row<100 && (lane&15)==0) atomicAdd(&sh_ge[row], v);
    }
  }
  __syncthreads();
  // ---- out = graph_emb @ Wo + bo : 512 threads, 4 k-chunks of 25 -----------
  if (tid < 512){
    int o = tid & 127, q = tid >> 7;           // lanes consecutive in o -> coalesced
    float s = 0.0f;
    int k0 = 25*q;
#pragma unroll 5
    for (int k=k0; k<k0+25; ++k) s += sh_ge[k]*Wo[k*OUT_+o];
    sh_part[q][o] = s;
  }
  __syncthreads();
  if (tid < OUT_){
    out[(size_t)b*OUT_ + tid] = bo[tid] + sh_part[0][tid] + sh_part[1][tid]
                              + sh_part[2][tid] + sh_part[3][tid];
  }
}

extern "C" void kernel_launch(void* const* d_in, const int* in_sizes, int n_in,
                              void* d_out, int out_size, void* d_ws, size_t ws_size,
                              hipStream_t stream){
  const float* nodes = (const float*)d_in[0];
  const float* edges = (const float*)d_in[1];
  const float* W_msg = (const float*)d_in[2];
  const float* W_ih  = (const float*)d_in[3];
  const float* W_hh  = (const float*)d_in[4];
  const float* b_ih  = (const float*)d_in[5];
  const float* b_hh  = (const float*)d_in[6];
  const float* Wg    = (const float*)d_in[7];
  const float* bg    = (const float*)d_in[8];
  const float* We    = (const float*)d_in[9];
  const float* be    = (const float*)d_in[10];
  const float* Wo    = (const float*)d_in[11];
  const float* bo    = (const float*)d_in[12];

  short* AF = (short*)d_ws;                 // 343*1024 shorts = 686 KB

  prep_frags<<<(NBLK*64 + 255)/256, 256, 0, stream>>>(W_msg, W_ih, W_hh, Wg, We, AF);
  mpnn_mfma<<<B_, TB, 0, stream>>>(nodes, edges, AF, b_ih, b_hh, bg, be, Wo, bo,
                                   (float*)d_out);
}

// Round 11
// 135.195 us; speedup vs baseline: 1.4051x; 1.0323x over previous
//
#include <hip/hip_runtime.h>
#include <cstddef>
#include <cstdint>

// B=256, N=32, F=40, H=M=100, EF=4, OUT=128, 3 passes.
#define B_   256
#define N_   32
#define F_   40
#define H_   100
#define OUT_ 128
#define CAP_ 8
#define TB   1024         // 16 waves/block -> 4 waves/SIMD, 1 block/CU
#define XCS  168          // Xcat row stride (shorts)
#define XMS  136          // Xm / Xy row stride (shorts)
#define NBLK 343
#define NLO  63           // readout blocks (280..342) carry lo fragments

using bf16x8 = __attribute__((ext_vector_type(8))) short;   // 8 bf16 (4 VGPRs)
using f32x4  = __attribute__((ext_vector_type(4))) float;   // MFMA C/D

__device__ __forceinline__ float sigmoidf_(float x){ return 1.0f/(1.0f+__expf(-x)); }
__device__ __forceinline__ float bf2f(short s){ return __uint_as_float(((uint32_t)(uint16_t)s)<<16); }
__device__ __forceinline__ short f2bf(float x){            // round-to-nearest-even
  uint32_t u = __float_as_uint(x);
  return (short)((u + 0x7FFFu + ((u>>16)&1u))>>16);
}
__device__ __forceinline__ void bsplit(float x, short& hi, short& lo){
  hi = f2bf(x);
  lo = f2bf(x - bf2f(hi));
}

// ---------------------------------------------------------------------------
// Weight pre-pack, v2: COALESCED READS (thread = source element), scattered
// 2-byte writes (L2 absorbs). Dense hi-only blocks of 1 KB (lane*8+j shorts);
// lo stored only for readout blocks 280.. (separate AFlo region).
// Block table (same as before):
//   [0,112)   W_msg : t*28 + (m>>4)*4 + (h>>5)          A[m][k=h]=W_msg[m,h,t]
//   [112,280) GRU   : 112+mat*28+(mg>>4)*4+(k>>5)       mat: ihr,ihz,ihn,hhr,hhz,hhn
//   [280,315) Wg^T  : 280+(j>>4)*5+(k>>5)  (K=140)      A[j][k]=Wg[k,j]  (hi+lo)
//   [315,343) We^T  : 315+(j>>4)*4+(k>>5)               A[j][k]=We[k,j]  (hi+lo)
// Lane map: A[m=lane&15][k=(lane>>4)*8+j]. OOR slots pre-zeroed by memset.
// ---------------------------------------------------------------------------
__global__ void prep_frags2(const float* __restrict__ Wmsg,
                            const float* __restrict__ Wih,
                            const float* __restrict__ Whh,
                            const float* __restrict__ Wg,
                            const float* __restrict__ We,
                            short* __restrict__ AFhi,
                            short* __restrict__ AFlo){
  int i = blockIdx.x*blockDim.x + threadIdx.x;
  if (i < 40000){                               // W_msg
    float v = Wmsg[i];
    int t = i&3, mk = i>>2, h = mk%100, m = mk/100;
    int blk = t*28 + (m>>4)*4 + (h>>5);
    int lane = (m&15) + (((h&31)>>3)<<4);
    AFhi[(size_t)blk*512 + lane*8 + (h&7)] = f2bf(v);
  } else if (i < 70000){                        // W_ih
    int i2 = i-40000;
    float v = Wih[i2];
    int jrow = i2/100, k = i2%100, mat = jrow/100, mg = jrow%100;
    int blk = 112 + mat*28 + (mg>>4)*4 + (k>>5);
    int lane = (mg&15) + (((k&31)>>3)<<4);
    AFhi[(size_t)blk*512 + lane*8 + (k&7)] = f2bf(v);
  } else if (i < 100000){                       // W_hh
    int i2 = i-70000;
    float v = Whh[i2];
    int jrow = i2/100, k = i2%100, mat = 3 + jrow/100, mg = jrow%100;
    int blk = 112 + mat*28 + (mg>>4)*4 + (k>>5);
    int lane = (mg&15) + (((k&31)>>3)<<4);
    AFhi[(size_t)blk*512 + lane*8 + (k&7)] = f2bf(v);
  } else if (i < 114000){                       // Wg (140x100), hi+lo
    int i2 = i-100000;
    float v = Wg[i2];
    int k = i2/100, j = i2%100;
    int blk = 280 + (j>>4)*5 + (k>>5);
    int lane = (j&15) + (((k&31)>>3)<<4);
    short hi,lo; bsplit(v,hi,lo);
    AFhi[(size_t)blk*512 + lane*8 + (k&7)] = hi;
    AFlo[(size_t)(blk-280)*512 + lane*8 + (k&7)] = lo;
  } else if (i < 124000){                       // We (100x100), hi+lo
    int i2 = i-114000;
    float v = We[i2];
    int k = i2/100, j = i2%100;
    int blk = 315 + (j>>4)*4 + (k>>5);
    int lane = (j&15) + (((k&31)>>3)<<4);
    short hi,lo; bsplit(v,hi,lo);
    AFhi[(size_t)blk*512 + lane*8 + (k&7)] = hi;
    AFlo[(size_t)(blk-280)*512 + lane*8 + (k&7)] = lo;
  }
}

// B-operand fragment from LDS [n][k] bf16: lane holds B[k=(lane>>4)*8+j][n=lane&15]
__device__ __forceinline__ bf16x8 ldB(const short* X, int stride, int nt, int ks, int lane){
  int n = nt*16 + (lane&15);
  return *(const bf16x8*)&X[n*stride + ks*32 + (lane>>4)*8];
}
// C += Ahi*(Bhi + Blo) : A in bf16 only (rel err <= 2^-9) -- msg/GRU path
__device__ __forceinline__ f32x4 mm2(const short* __restrict__ AFhi, int blk, int lane,
                                     bf16x8 bh, bf16x8 bl, f32x4 c){
  bf16x8 ah = *(const bf16x8*)(AFhi + (size_t)blk*512 + lane*8);
  c = __builtin_amdgcn_mfma_f32_16x16x32_bf16(ah, bh, c, 0,0,0);
  c = __builtin_amdgcn_mfma_f32_16x16x32_bf16(ah, bl, c, 0,0,0);
  return c;
}
// full split-bf16 triple product (readout path)
__device__ __forceinline__ f32x4 mm3r(const short* __restrict__ AFhi,
                                      const short* __restrict__ AFlo,
                                      int blk, int lane, bf16x8 bh, bf16x8 bl, f32x4 c){
  bf16x8 ah = *(const bf16x8*)(AFhi + (size_t)blk*512 + lane*8);
  bf16x8 al = *(const bf16x8*)(AFlo + (size_t)(blk-280)*512 + lane*8);
  c = __builtin_amdgcn_mfma_f32_16x16x32_bf16(ah, bh, c, 0,0,0);
  c = __builtin_amdgcn_mfma_f32_16x16x32_bf16(ah, bl, c, 0,0,0);
  c = __builtin_amdgcn_mfma_f32_16x16x32_bf16(al, bh, c, 0,0,0);
  return c;
}

// ---------------------------------------------------------------------------
// Fused MPNN, one block per batch, 1024 threads (16 waves), 14 tile-tasks.
// 3 barriers/pass: [Y-build] bar [msg-mm2 + hh-mm2 + Xm-write] bar
// [ih-mm2 + GRU elementwise -> Xc] bar.  (hh reads Xc before any region-2
// write; each wave's elementwise touches only its own (row,n) cells.)
// All multi-mm loops #pragma unroll 1 (spill guard, R6-R9: hoisted A-loads
// past the 64-arch-VGPR cap cost 22-57 MB scratch traffic).
// ---------------------------------------------------------------------------
__global__ __launch_bounds__(TB, 4) void mpnn_mfma(
    const float* __restrict__ nodes, const float* __restrict__ edges,
    const short* __restrict__ AFhi, const short* __restrict__ AFlo,
    const float* __restrict__ b_ih, const float* __restrict__ b_hh,
    const float* __restrict__ bg, const float* __restrict__ be,
    const float* __restrict__ Wo, const float* __restrict__ bo,
    float* __restrict__ out){
  const int b = blockIdx.x;
  const int tid = threadIdx.x;
  const int lane = tid & 63;
  const int w = tid >> 6;

  __shared__ short XcH[32*XCS], XcL[32*XCS];      // cat: h | nodes(100..139) | 0
  __shared__ short XmH[32*XMS], XmL[32*XMS];      // messages
  __shared__ short XyH[4][32*XMS], XyL[4][32*XMS];// per-type aggregated Y_t
  __shared__ float sh_ge[H_];
  __shared__ float sh_part[4][OUT_];              // Wo-tail partials
  __shared__ float sh_rowsum[N_];
  __shared__ int   sh_cnt[N_];
  __shared__ int   sh_gt[N_][CAP_];               // packed (g<<2)|t
  __shared__ float sh_w[N_][CAP_];

  // ---- zero LDS (Xc rows>=140 and Xm rows>=100 must stay 0) ----------------
  for (int i=tid;i<(32*XCS)/2;i+=TB){ ((int*)XcH)[i]=0; ((int*)XcL)[i]=0; }
  for (int i=tid;i<(32*XMS)/2;i+=TB){ ((int*)XmH)[i]=0; ((int*)XmL)[i]=0; }
  if (tid < H_) sh_ge[tid]=0.0f;
  if (tid < N_){ sh_cnt[tid]=0; sh_rowsum[tid]=0.0f; }
  __syncthreads();

  // ---- per-node neighbor lists + node staging ------------------------------
  for (int p=tid; p<N_*N_; p+=TB){
    int n = p>>5, g = p&31;
    const float4 ev = *(const float4*)(edges + (((size_t)b*N_+n)*N_+g)*4);
    float adj = ev.x+ev.y+ev.z+ev.w;
    if (adj != 0.0f){
      atomicAdd(&sh_rowsum[n], adj);
      float ef[4] = {ev.x,ev.y,ev.z,ev.w};
      for (int f=0; f<4; ++f)
        if (ef[f] != 0.0f){
          int s = atomicAdd(&sh_cnt[n],1);
          if (s<CAP_){ sh_gt[n][s]=(g<<2)|f; sh_w[n][s]=ef[f]; }
        }
    }
  }
  for (int p=tid; p<N_*F_; p+=TB){
    int n = p/F_, f = p%F_;
    float x = nodes[((size_t)b*N_+n)*F_ + f];
    short hi,lo; bsplit(x,hi,lo);
    XcH[n*XCS+f]=hi;      XcL[n*XCS+f]=lo;        // h init rows 0..39
    XcH[n*XCS+100+f]=hi;  XcL[n*XCS+100+f]=lo;    // cat-tail rows 100..139
  }
  __syncthreads();

  const int jmt = w>>1, nt = w&1;                 // task (w<14)
  const bool task = (w < 14);

  for (int pass=0; pass<3; ++pass){
    // ---- build ALL Y_t in one sweep: n wave-uniform, lanes along k ---------
    for (int it=0; it<2; ++it){
      int idx = tid + it*TB;                   // 0..2047
      int n = idx >> 6;                        // wave-uniform
      int kp = idx & 63;                       // int index: k = 2kp, 2kp+1
      int cnt = sh_cnt[n] < CAP_ ? sh_cnt[n] : CAP_;
      float s0[4]={0,0,0,0}, s1[4]={0,0,0,0};
      for (int e=0;e<cnt;++e){
        int gt = sh_gt[n][e];                  // wave-uniform -> scalar branch
        int g = gt>>2; float wv = sh_w[n][e];
        int hh = ((const int*)(XcH + g*XCS))[kp];
        int ll = ((const int*)(XcL + g*XCS))[kp];
        float h0 = bf2f((short)(hh&0xffff)) + bf2f((short)(ll&0xffff));
        float h1 = bf2f((short)(hh>>16))    + bf2f((short)(ll>>16));
        int t = gt&3;
        if (t==0)      { s0[0]+=wv*h0; s1[0]+=wv*h1; }
        else if (t==1) { s0[1]+=wv*h0; s1[1]+=wv*h1; }
        else if (t==2) { s0[2]+=wv*h0; s1[2]+=wv*h1; }
        else           { s0[3]+=wv*h0; s1[3]+=wv*h1; }
      }
#pragma unroll
      for (int t=0;t<4;++t){
        short a,b2,c,d; bsplit(s0[t],a,b2); bsplit(s1[t],c,d);
        ((int*)(XyH[t] + n*XMS))[kp] = (int)((uint16_t)a  | ((uint32_t)(uint16_t)c<<16));
        ((int*)(XyL[t] + n*XMS))[kp] = (int)((uint16_t)b2 | ((uint32_t)(uint16_t)d<<16));
      }
    }
    __syncthreads();
    // ---- region 1: messages mm2 (dual chain) + GRU hh mm2 + Xm write -------
    f32x4 Ch0=(f32x4)0.0f, Ch1=(f32x4)0.0f, Ch2=(f32x4)0.0f;   // hh_r/z/n
    if (task){
      f32x4 Cm0=(f32x4)0.0f, Cm1=(f32x4)0.0f;
#pragma unroll 1
      for (int i=0;i<8;++i){                   // t=0,1
        int t = i>>2, ks = i&3;
        bf16x8 bh = ldB(XyH[t],XMS,nt,ks,lane), bl = ldB(XyL[t],XMS,nt,ks,lane);
        Cm0 = mm2(AFhi, (t*7+jmt)*4+ks, lane, bh, bl, Cm0);
      }
#pragma unroll 1
      for (int i=8;i<16;++i){                  // t=2,3
        int t = i>>2, ks = i&3;
        bf16x8 bh = ldB(XyH[t],XMS,nt,ks,lane), bl = ldB(XyL[t],XMS,nt,ks,lane);
        Cm1 = mm2(AFhi, (t*7+jmt)*4+ks, lane, bh, bl, Cm1);
      }
#pragma unroll 1
      for (int g=0; g<3; ++g){                 // hh gates (reads Xc only)
        f32x4 Cb=(f32x4)0.0f;
#pragma unroll 1
        for (int ks=0;ks<4;++ks){
          bf16x8 bhh = ldB(XcH,XCS,nt,ks,lane), bhl = ldB(XcL,XCS,nt,ks,lane);
          Cb = mm2(AFhi, 112+(g+3)*28+jmt*4+ks, lane, bhh, bhl, Cb);
        }
        if (g==0) Ch0=Cb; else if (g==1) Ch1=Cb; else Ch2=Cb;
      }
      f32x4 Cm = Cm0 + Cm1;
      int n = nt*16+(lane&15);                 // Xm write (disjoint from Xy/Xc)
      for (int r=0;r<4;++r){
        int row = jmt*16 + (lane>>4)*4 + r;
        if (row<100){
          short hi,lo; bsplit(Cm[r],hi,lo);
          XmH[n*XMS+row]=hi; XmL[n*XMS+row]=lo;
        }
      }
    }
    __syncthreads();
    // ---- region 2: ih mm2 + GRU elementwise (own cells of Xc) --------------
    if (task){
      f32x4 Ci0=(f32x4)0.0f, Ci1=(f32x4)0.0f, Ci2=(f32x4)0.0f;
#pragma unroll 1
      for (int g=0; g<3; ++g){
        f32x4 Ca=(f32x4)0.0f;
#pragma unroll 1
        for (int ks=0;ks<4;++ks){
          bf16x8 bmh = ldB(XmH,XMS,nt,ks,lane), bml = ldB(XmL,XMS,nt,ks,lane);
          Ca = mm2(AFhi, 112+g*28+jmt*4+ks, lane, bmh, bml, Ca);
        }
        if (g==0) Ci0=Ca; else if (g==1) Ci1=Ca; else Ci2=Ca;
      }
      int n = nt*16+(lane&15);
      bool msk = (sh_rowsum[n] != 0.0f);
      for (int r=0;r<4;++r){
        int row = jmt*16 + (lane>>4)*4 + r;
        if (row<100){
          float ho = bf2f(XcH[n*XCS+row]) + bf2f(XcL[n*XCS+row]);
          float rr = sigmoidf_(Ci0[r]+Ch0[r] + b_ih[row]     + b_hh[row]);
          float zz = sigmoidf_(Ci1[r]+Ch1[r] + b_ih[100+row] + b_hh[100+row]);
          float nn = tanhf(Ci2[r] + b_ih[200+row] + rr*(Ch2[r] + b_hh[200+row]));
          float hnew = (1.0f-zz)*nn + zz*ho;
          if (!msk) hnew = ho;
          short hi,lo; bsplit(hnew,hi,lo);
          XcH[n*XCS+row]=hi; XcL[n*XCS+row]=lo;
        }
      }
    }
    __syncthreads();
  }

  // ---- readout: gate = sig(cat@Wg+bg), emb = gate*(h@We+be), masked sum ----
  f32x4 Cg=(f32x4)0.0f, Ce=(f32x4)0.0f;
  if (task){
#pragma unroll 1
    for (int ks=0;ks<5;++ks){                  // K=140: Xcat carries cat rows
      bf16x8 bh = ldB(XcH,XCS,nt,ks,lane), bl = ldB(XcL,XCS,nt,ks,lane);
      Cg = mm3r(AFhi, AFlo, 280 + jmt*5 + ks, lane, bh, bl, Cg);
    }
#pragma unroll 1
    for (int ks=0;ks<4;++ks){                  // K=100: We zero-pad kills rows>=100
      bf16x8 bh = ldB(XcH,XCS,nt,ks,lane), bl = ldB(XcL,XCS,nt,ks,lane);
      Ce = mm3r(AFhi, AFlo, 315 + jmt*4 + ks, lane, bh, bl, Ce);
    }
    int n = nt*16+(lane&15);
    bool msk = (sh_rowsum[n] != 0.0f);
    for (int r=0;r<4;++r){
      int row = jmt*16 + (lane>>4)*4 + r;
      float v = 0.0f;
      if (row<100){
        float gate = sigmoidf_(Cg[r] + bg[row]);
        float emb  = gate*(Ce[r] + be[row]);
        v = msk ? emb : 0.0f;
      }
      v += __shfl_xor(v, 1);                   // reduce across 16 cols
      v += __shfl_xor(v, 2);
      v += __shfl_xor(v, 4);
      v += __shfl_xor(v, 8);
      if (row<100 && (lane&15)==0) atomicAdd(&sh_ge[row], v);
    }
  }
  __syncthreads();
  // ---- out = graph_emb @ Wo + bo : 512 threads, 4 k-chunks of 25 -----------
  if (tid < 512){
    int o = tid & 127, q = tid >> 7;           // lanes consecutive in o -> coalesced
    float s = 0.0f;
    int k0 = 25*q;
#pragma unroll 5
    for (int k=k0; k<k0+25; ++k) s += sh_ge[k]*Wo[k*OUT_+o];
    sh_part[q][o] = s;
  }
  __syncthreads();
  if (tid < OUT_){
    out[(size_t)b*OUT_ + tid] = bo[tid] + sh_part[0][tid] + sh_part[1][tid]
                              + sh_part[2][tid] + sh_part[3][tid];
  }
}

extern "C" void kernel_launch(void* const* d_in, const int* in_sizes, int n_in,
                              void* d_out, int out_size, void* d_ws, size_t ws_size,
                              hipStream_t stream){
  const float* nodes = (const float*)d_in[0];
  const float* edges = (const float*)d_in[1];
  const float* W_msg = (const float*)d_in[2];
  const float* W_ih  = (const float*)d_in[3];
  const float* W_hh  = (const float*)d_in[4];
  const float* b_ih  = (const float*)d_in[5];
  const float* b_hh  = (const float*)d_in[6];
  const float* Wg    = (const float*)d_in[7];
  const float* bg    = (const float*)d_in[8];
  const float* We    = (const float*)d_in[9];
  const float* be    = (const float*)d_in[10];
  const float* Wo    = (const float*)d_in[11];
  const float* bo    = (const float*)d_in[12];

  short* AFhi = (short*)d_ws;                        // 343*512 shorts = 343 KB
  short* AFlo = AFhi + (size_t)NBLK*512;             //  63*512 shorts =  63 KB
  size_t af_bytes = ((size_t)NBLK + NLO) * 512 * sizeof(short);

  hipMemsetAsync(d_ws, 0, af_bytes, stream);         // zero OOR fragment slots
  prep_frags2<<<(124000 + 255)/256, 256, 0, stream>>>(W_msg, W_ih, W_hh, Wg, We,
                                                      AFhi, AFlo);
  mpnn_mfma<<<B_, TB, 0, stream>>>(nodes, edges, AFhi, AFlo, b_ih, b_hh, bg, be,
                                   Wo, bo, (float*)d_out);
}